// Round 10
// baseline (4253.679 us; speedup 1.0000x reference)
//
#include <hip/hip_runtime.h>

__device__ __forceinline__ float lrelu(float x) { return x >= 0.f ? x : 0.2f * x; }

// ---------------------------------------------------------------------------
// conv0: fp32 x (4,3,256,256) (half batch), w (64,3,3,3), s1 p1, +bias+lrelu
// -> ACTIVATED fp32 unpadded (4,64,256,256)
// ---------------------------------------------------------------------------
__global__ __launch_bounds__(256) void conv0_k(const float* __restrict__ x,
                                               const float* __restrict__ w,
                                               const float* __restrict__ bias,
                                               float* __restrict__ out) {
    __shared__ float sIn[3][34][34];
    __shared__ float sW[27][16];
    const int H = 256;
    int tid = threadIdx.x, tx = tid & 31, ty = tid >> 5;
    int tX = (blockIdx.x & 7) * 32, tY = (blockIdx.x >> 3) * 32;
    int b = blockIdx.y, cog = blockIdx.z * 16;
    float acc[4][16] = {};
    const float* inB = x + (size_t)b * 3 * H * H;
    for (int idx = tid; idx < 3 * 1156; idx += 256) {
        int ci = idx / 1156, r = idx % 1156, iy = r / 34, ix = r % 34;
        int gy = tY - 1 + iy, gx = tX - 1 + ix;
        float v = 0.f;
        if ((unsigned)gy < 256u && (unsigned)gx < 256u)
            v = inB[(ci * H + gy) * H + gx];
        sIn[ci][iy][ix] = v;
    }
    for (int idx = tid; idx < 27 * 16; idx += 256) {
        int co = idx & 15, rest = idx >> 4;
        sW[rest][co] = w[(cog + co) * 27 + rest];
    }
    __syncthreads();
#pragma unroll
    for (int ci = 0; ci < 3; ci++)
#pragma unroll
        for (int dy = 0; dy < 3; dy++)
#pragma unroll
            for (int dx = 0; dx < 3; dx++) {
                float a0 = sIn[ci][ty + dy][tx + dx];
                float a1 = sIn[ci][ty + 8 + dy][tx + dx];
                float a2 = sIn[ci][ty + 16 + dy][tx + dx];
                float a3 = sIn[ci][ty + 24 + dy][tx + dx];
                const float* wp = sW[ci * 9 + dy * 3 + dx];
#pragma unroll
                for (int co = 0; co < 16; co++) {
                    float wv = wp[co];
                    acc[0][co] += a0 * wv; acc[1][co] += a1 * wv;
                    acc[2][co] += a2 * wv; acc[3][co] += a3 * wv;
                }
            }
    float* outB = out + ((size_t)b * 64 + cog) * H * H;
#pragma unroll
    for (int co = 0; co < 16; co++) {
        float bv = bias[cog + co];
#pragma unroll
        for (int r = 0; r < 4; r++)
            outB[(co * H + (tY + ty + 8 * r)) * H + tX + tx] =
                lrelu(acc[r][co] + bv);
    }
}

// ---------------------------------------------------------------------------
// Unified 3x3 s1 conv, 6-row register reuse (4 consecutive output rows per
// thread), double-buffered LDS, 1 barrier per 2-cin step.
// NOTE: no min-waves bound — R8 proved capping VGPR at 64 spills the
// accumulators to scratch (22 GB HBM traffic/dispatch, 3.4x slowdown).
// R10: COG=16 doubles FMA per ds_read group and halves staging/block.
// Per-output FMA order is unchanged -> bit-identical results vs COG=8.
// ---------------------------------------------------------------------------
template <int COG, bool PADDED>
__global__ __launch_bounds__(256) void c3x3_k(const float* __restrict__ in,
                                              const float* __restrict__ w,
                                              const float2* __restrict__ ss,
                                              float* __restrict__ out,
                                              int Cin, int Cout, int H,
                                              int Hp, int Wp,
                                              int oHp, int oWp, int oOff) {
    constexpr int RS = PADDED ? 36 : 34;      // LDS row stride (floats)
    constexpr int CI = 34 * RS;               // per-cin LDS floats
    __shared__ float sIn[2][2 * CI];
    __shared__ float sW[2][18 * COG];
    const int tid = threadIdx.x, tx = tid & 31, ty = tid >> 5;  // ty: 8 bands
    const int tpr = H >> 5;
    const int tX = (blockIdx.x % tpr) * 32, tY = (blockIdx.x / tpr) * 32;
    const int b = blockIdx.y, cog = blockIdx.z * COG;
    const int HWin = Hp * Wp;
    const float* inB = in + (size_t)b * Cin * HWin;

    constexpr int NSTG = PADDED ? 3 : 10;
    int gOff[NSTG]; int lOff[NSTG]; float fm[NSTG]; int cis[NSTG]; bool act[NSTG];
#pragma unroll
    for (int r = 0; r < NSTG; r++) {
        int idx = tid + r * 256;
        if (PADDED) {
            bool a = idx < 612;               // 2 cins x 34 rows x 9 float4
            int ci = idx / 306, rem = idx % 306;
            int row = rem / 9, c4 = rem % 9;
            gOff[r] = a ? (ci * HWin + (tY + row) * Wp + tX + 4 * c4) : 0;
            lOff[r] = ci * CI + row * RS + 4 * c4;
            act[r] = a; fm[r] = 1.f; cis[r] = ci;
        } else {
            int ci = idx / 1156, rem = idx % 1156;
            int iy = rem / 34, ix = rem % 34;
            int gy = tY - 1 + iy, gx = tX - 1 + ix;
            bool ok = (idx < 2312) && ((unsigned)gy < (unsigned)H) &&
                      ((unsigned)gx < (unsigned)H);
            gOff[r] = ok ? (ci * HWin + gy * Wp + gx) : 0;
            lOff[r] = idx;                    // == ci*CI + iy*RS + ix
            fm[r] = ok ? 1.f : 0.f;
            cis[r] = ci; act[r] = idx < 2312;
        }
    }
    constexpr int NW = (18 * COG + 255) / 256;
    int wgo[NW]; bool wact[NW];
#pragma unroll
    for (int r = 0; r < NW; r++) {
        int widx = tid + r * 256;
        bool a = widx < 18 * COG;
        int co = widx % COG, rest = widx / COG;   // rest = ci*9 + t
        int ci = rest / 9, t = rest % 9;
        wgo[r] = a ? (((cog + co) * Cin + ci) * 9 + t) : 0;
        wact[r] = a;
    }

    float acc[4][COG];
#pragma unroll
    for (int j = 0; j < 4; j++)
#pragma unroll
        for (int c = 0; c < COG; c++) acc[j][c] = 0.f;

    const int steps = Cin >> 1;

    // ---- stage step 0 -> buf 0
    {
        float pw[NW];
#pragma unroll
        for (int r = 0; r < NW; r++) pw[r] = w[wgo[r]];
        if (PADDED) {
            float4 pf[NSTG];
#pragma unroll
            for (int r = 0; r < NSTG; r++)
                pf[r] = *reinterpret_cast<const float4*>(inB + gOff[r]);
#pragma unroll
            for (int r = 0; r < NSTG; r++)
                if (act[r]) *reinterpret_cast<float4*>(&sIn[0][lOff[r]]) = pf[r];
        } else {
            float pf[NSTG];
#pragma unroll
            for (int r = 0; r < NSTG; r++) pf[r] = inB[gOff[r]];
#pragma unroll
            for (int r = 0; r < NSTG; r++)
                if (act[r]) {
                    float2 t = ss[cis[r]];
                    float v = t.x * pf[r] + t.y;
                    sIn[0][lOff[r]] = (v >= 0.f ? v : 0.2f * v) * fm[r];
                }
        }
#pragma unroll
        for (int r = 0; r < NW; r++)
            if (wact[r]) sW[0][tid + r * 256] = pw[r];
    }
    __syncthreads();

    for (int k = 0; k < steps; k++) {
        const int cur = k & 1;
        const bool more = (k + 1) < steps;
        float4 pf4[PADDED ? NSTG : 1];
        float pfs[PADDED ? 1 : NSTG];
        float pw[NW]; float2 t0, t1;
        if (more) {
            const int c0n = 2 * (k + 1);
            const float* p = inB + (size_t)c0n * HWin;
            const float* wp2 = w + (size_t)c0n * 9;
#pragma unroll
            for (int r = 0; r < NW; r++) pw[r] = wp2[wgo[r]];
            if (PADDED) {
#pragma unroll
                for (int r = 0; r < NSTG; r++)
                    pf4[r] = *reinterpret_cast<const float4*>(p + gOff[r]);
            } else {
                t0 = ss[c0n]; t1 = ss[c0n + 1];
#pragma unroll
                for (int r = 0; r < NSTG; r++) pfs[r] = p[gOff[r]];
            }
        }
        // ---- compute on buf cur (6-row register reuse)
        const float* sI = sIn[cur];
        const float* sw = sW[cur];
#pragma unroll
        for (int ci = 0; ci < 2; ci++)
#pragma unroll
            for (int dx = 0; dx < 3; dx++) {
                const float* bp = sI + ci * CI + (4 * ty) * RS + tx + dx;
                float a[6];
#pragma unroll
                for (int j = 0; j < 6; j++) a[j] = bp[j * RS];
#pragma unroll
                for (int dy = 0; dy < 3; dy++) {
                    const float* wp = sw + (ci * 9 + dy * 3 + dx) * COG;
#pragma unroll
                    for (int c = 0; c < COG; c++) {
                        float wv = wp[c];
                        acc[0][c] += a[0 + dy] * wv;
                        acc[1][c] += a[1 + dy] * wv;
                        acc[2][c] += a[2 + dy] * wv;
                        acc[3][c] += a[3 + dy] * wv;
                    }
                }
            }
        if (more) {
            const int nb = cur ^ 1;
            if (PADDED) {
#pragma unroll
                for (int r = 0; r < NSTG; r++)
                    if (act[r])
                        *reinterpret_cast<float4*>(&sIn[nb][lOff[r]]) = pf4[r];
            } else {
#pragma unroll
                for (int r = 0; r < NSTG; r++)
                    if (act[r]) {
                        float2 t = cis[r] ? t1 : t0;
                        float v = t.x * pfs[r] + t.y;
                        sIn[nb][lOff[r]] = (v >= 0.f ? v : 0.2f * v) * fm[r];
                    }
            }
#pragma unroll
            for (int r = 0; r < NW; r++)
                if (wact[r]) sW[nb][tid + r * 256] = pw[r];
        }
        __syncthreads();
    }

    float* outB = out + (size_t)(b * Cout + cog) * oHp * oWp;
#pragma unroll
    for (int c = 0; c < COG; c++)
#pragma unroll
        for (int j = 0; j < 4; j++)
            outB[(size_t)c * oHp * oWp +
                 (size_t)(tY + 4 * ty + j + oOff) * oWp + tX + tx + oOff] =
                acc[j][c];
}

// ---------------------------------------------------------------------------
// R5-proven 4x4 s2 p1 conv, masked staging, dbuf; output padded via
// oHp/oWp/oOff. XFORM applies lrelu(scale*x+shift) on load. (conv1, conv3)
// ---------------------------------------------------------------------------
template <int COG, bool XFORM>
__global__ __launch_bounds__(256) void conv4x4_k(const float* __restrict__ in,
                                                 const float* __restrict__ w,
                                                 const float2* __restrict__ ss,
                                                 float* __restrict__ out,
                                                 int Cin, int Hin,
                                                 int Cout, int oHp, int oWp,
                                                 int oOff) {
    __shared__ float sInF[2 * 4356];
    __shared__ float sWF[2 * 16 * COG];
    const int Hout = Hin >> 1;
    const int tid = threadIdx.x, tx = tid & 31, ty = tid >> 5;
    const int tpr = Hout >> 5;
    const int tX = (blockIdx.x % tpr) * 32, tY = (blockIdx.x / tpr) * 32;
    const int b = blockIdx.y, cog = blockIdx.z * COG;
    const int oy = 2 * tY - 1, ox = 2 * tX - 1;
    const int HH = Hin * Hin;
    const float* inB = in + (size_t)b * Cin * HH;

    constexpr int NS = 18;
    int soff[NS]; float fm[NS];
#pragma unroll
    for (int r = 0; r < NS; r++) {
        int idx = tid + r * 256;
        int iy = idx / 66, ix = idx % 66;
        int gy = oy + iy, gx = ox + ix;
        bool ok = (idx < 4356) && ((unsigned)gy < (unsigned)Hin) &&
                  ((unsigned)gx < (unsigned)Hin);
        soff[r] = ok ? (gy * Hin + gx) : 0;
        fm[r] = ok ? 1.f : 0.f;
    }
    constexpr int NW = (16 * COG + 255) / 256;
    int wgo[NW];
#pragma unroll
    for (int r = 0; r < NW; r++) {
        int widx = tid + r * 256;
        int co = widx % COG, t = widx / COG;
        wgo[r] = ((cog + co) * Cin) * 16 + t;
    }

    float acc[4][COG];
#pragma unroll
    for (int r = 0; r < 4; r++)
#pragma unroll
        for (int c = 0; c < COG; c++) acc[r][c] = 0.f;

    {
        float pf[NS]; float pw[NW];
        float2 tt = XFORM ? ss[0] : make_float2(1.f, 0.f);
#pragma unroll
        for (int r = 0; r < NS; r++) pf[r] = inB[soff[r]];
#pragma unroll
        for (int r = 0; r < NW; r++)
            pw[r] = (tid + r * 256 < 16 * COG) ? w[wgo[r]] : 0.f;
#pragma unroll
        for (int r = 0; r < NS; r++)
            if (tid + r * 256 < 4356) {
                float v = pf[r];
                if (XFORM) { v = tt.x * v + tt.y; v = (v >= 0.f ? v : 0.2f * v); }
                sInF[tid + r * 256] = v * fm[r];
            }
#pragma unroll
        for (int r = 0; r < NW; r++)
            if (tid + r * 256 < 16 * COG) sWF[tid + r * 256] = pw[r];
    }
    __syncthreads();

    for (int k = 0; k < Cin; k++) {
        const int cur = k & 1;
        const bool more = (k + 1) < Cin;
        float pf[NS]; float pw[NW]; float2 tt;
        if (more) {
            const int c0n = k + 1;
            const float* p = inB + (size_t)c0n * HH;
            if (XFORM) tt = ss[c0n];
#pragma unroll
            for (int r = 0; r < NS; r++) pf[r] = p[soff[r]];
#pragma unroll
            for (int r = 0; r < NW; r++)
                pw[r] = (tid + r * 256 < 16 * COG) ? w[wgo[r] + c0n * 16] : 0.f;
        }
        const float* sI = sInF + cur * 4356;
        const float* sw = sWF + cur * 16 * COG;
#pragma unroll
        for (int dy = 0; dy < 4; dy++)
#pragma unroll
            for (int dx = 0; dx < 4; dx++) {
                const float* basep = sI + (2 * ty + dy) * 66 + 2 * tx + dx;
                float a0 = basep[0];
                float a1 = basep[16 * 66];
                float a2 = basep[32 * 66];
                float a3 = basep[48 * 66];
                const float* wp = sw + (dy * 4 + dx) * COG;
#pragma unroll
                for (int c = 0; c < COG; c++) {
                    float wv = wp[c];
                    acc[0][c] += a0 * wv; acc[1][c] += a1 * wv;
                    acc[2][c] += a2 * wv; acc[3][c] += a3 * wv;
                }
            }
        if (more) {
            const int nb = (cur ^ 1);
#pragma unroll
            for (int r = 0; r < NS; r++)
                if (tid + r * 256 < 4356) {
                    float v = pf[r];
                    if (XFORM) { v = tt.x * v + tt.y; v = (v >= 0.f ? v : 0.2f * v); }
                    sInF[nb * 4356 + tid + r * 256] = v * fm[r];
                }
#pragma unroll
            for (int r = 0; r < NW; r++)
                if (tid + r * 256 < 16 * COG)
                    sWF[nb * 16 * COG + tid + r * 256] = pw[r];
        }
        __syncthreads();
    }

    float* outB = out + (size_t)(b * Cout + cog) * oHp * oWp;
#pragma unroll
    for (int c = 0; c < COG; c++)
#pragma unroll
        for (int r = 0; r < 4; r++)
            outB[(size_t)c * oHp * oWp +
                 (size_t)(tY + ty + 8 * r + oOff) * oWp + tX + tx + oOff] =
                acc[r][c];
}

// ---------------------------------------------------------------------------
// BN batch stats (FP64 partials). Handles padded interior via Hp/Wp/off.
// ---------------------------------------------------------------------------
__global__ __launch_bounds__(256) void stats_k(const float* __restrict__ x,
                                               double2* __restrict__ part,
                                               int C, int hs, int ws,
                                               int Hp, int Wp, int off) {
    int c = blockIdx.y, s = blockIdx.x, S = gridDim.x;
    int H = 1 << hs, W = 1 << ws;
    int total = 8 << (hs + ws);
    int per = total / S;
    int lo = s * per;
    double sum = 0.0, sq = 0.0;
    for (int i = lo + threadIdx.x; i < lo + per; i += 256) {
        int b = i >> (hs + ws);
        int y = (i >> ws) & (H - 1);
        int xx = i & (W - 1);
        double v = x[((size_t)(b * C + c) * Hp + y + off) * Wp + xx + off];
        sum += v; sq += v * v;
    }
    __shared__ double s1[256], s2[256];
    s1[threadIdx.x] = sum; s2[threadIdx.x] = sq;
    __syncthreads();
    for (int o = 128; o; o >>= 1) {
        if (threadIdx.x < o) {
            s1[threadIdx.x] += s1[threadIdx.x + o];
            s2[threadIdx.x] += s2[threadIdx.x + o];
        }
        __syncthreads();
    }
    if (threadIdx.x == 0) { part[c * S + s].x = s1[0]; part[c * S + s].y = s2[0]; }
}

__global__ void bnfin_k(const double2* __restrict__ part, int S, int C, double invN,
                        const float* __restrict__ g, const float* __restrict__ bb,
                        float2* __restrict__ ss) {
    int c = threadIdx.x;
    if (c >= C) return;
    double sum = 0.0, sq = 0.0;
    for (int s = 0; s < S; s++) { double2 p = part[c * S + s]; sum += p.x; sq += p.y; }
    double m = sum * invN;
    double v = sq * invN - m * m;
    double sc = (double)g[c] / sqrt(v + 1e-5);
    ss[c] = make_float2((float)sc, (float)((double)bb[c] - m * sc));
}

// ---------------------------------------------------------------------------
// bnact: zero padded border + transform interior in place lrelu(sc*x+sh).
// ---------------------------------------------------------------------------
__global__ __launch_bounds__(256) void bnact_k(float* __restrict__ p,
                                               const float2* __restrict__ ss,
                                               int C, int H, int W,
                                               int Hp, int Wp) {
    int pc = blockIdx.x;
    int c = pc & (C - 1);
    float2 t = ss[c];
    float* pl = p + (size_t)pc * Hp * Wp;
    int n = Hp * Wp;
    for (int i = threadIdx.x; i < n; i += 256) {
        int y = i / Wp, x = i - y * Wp;
        bool inter = (y >= 1) && (y <= H) && (x >= 1) && (x <= W);
        if (!inter) pl[i] = 0.f;
        else { float v = pl[i]; pl[i] = lrelu(t.x * v + t.y); }
    }
}

// ---------------------------------------------------------------------------
// h6 raw (8,256,64,64) + BN6+lrelu -> tok (8,4096,256)
// ---------------------------------------------------------------------------
__global__ __launch_bounds__(256) void transp_k(const float* __restrict__ h6,
                                                const float2* __restrict__ ss,
                                                float* __restrict__ tok) {
    __shared__ float sT[32][33];
    int tx = threadIdx.x & 31, ty = threadIdx.x >> 5;
    int n0 = blockIdx.x * 32, d0 = blockIdx.y * 32, b = blockIdx.z;
    const float* hb = h6 + ((size_t)b * 256 + d0) * 4096 + n0;
#pragma unroll
    for (int r = 0; r < 4; r++) {
        int d = ty + 8 * r;
        float2 t = ss[d0 + d];
        sT[d][tx] = lrelu(t.x * hb[d * 4096 + tx] + t.y);
    }
    __syncthreads();
    float* tb = tok + ((size_t)b * 4096 + n0) * 256 + d0;
#pragma unroll
    for (int r = 0; r < 4; r++) {
        int n = ty + 8 * r;
        tb[n * 256 + tx] = sT[tx][n];
    }
}

// ---------------------------------------------------------------------------
// Token stage: gating argmax, selected-expert body slice, ortho, cls MLP.
// ---------------------------------------------------------------------------
__global__ __launch_bounds__(256) void token_k(const float* __restrict__ tok,
                                               const float* __restrict__ wg,
                                               const float* __restrict__ bw,
                                               const float* __restrict__ bb,
                                               const float* __restrict__ ow,
                                               const float* __restrict__ w1,
                                               const float* __restrict__ b1,
                                               const float* __restrict__ w2,
                                               const float* __restrict__ b2,
                                               float* __restrict__ outp) {
    __shared__ float sf[4][256];
    const int tid = threadIdx.x, wave = tid >> 6, l = tid & 63;
    const int t = blockIdx.x * 4 + wave;
    const float4 tv = reinterpret_cast<const float4*>(tok + (size_t)t * 256)[l];
    sf[wave][4 * l + 0] = tv.x; sf[wave][4 * l + 1] = tv.y;
    sf[wave][4 * l + 2] = tv.z; sf[wave][4 * l + 3] = tv.w;

    float lg[12];
#pragma unroll
    for (int e = 0; e < 12; e++) lg[e] = 0.f;
    const float tj[4] = {tv.x, tv.y, tv.z, tv.w};
#pragma unroll
    for (int j = 0; j < 4; j++) {
        const float* wr = wg + (4 * l + j) * 12;
#pragma unroll
        for (int e = 0; e < 12; e++) lg[e] += tj[j] * wr[e];
    }
#pragma unroll
    for (int off = 32; off > 0; off >>= 1) {
#pragma unroll
        for (int e = 0; e < 12; e++) lg[e] += __shfl_xor(lg[e], off);
    }
    int idx = 0; float best = lg[0];
#pragma unroll
    for (int e = 1; e < 12; e++)
        if (lg[e] > best) { best = lg[e]; idx = e; }
    const int cb = idx * 256;

    float f0 = 0.f, f1 = 0.f, f2 = 0.f, f3 = 0.f;
    const float* bwp = bw + cb + 4 * l;
#pragma unroll 4
    for (int d = 0; d < 256; d++) {
        const float td = sf[wave][d];
        const float4 wv = *reinterpret_cast<const float4*>(bwp + (size_t)d * 3072);
        f0 += td * wv.x; f1 += td * wv.y;
        f2 += td * wv.z; f3 += td * wv.w;
    }
    float fj[4] = {f0, f1, f2, f3};
#pragma unroll
    for (int j = 0; j < 4; j++) {
        int jj = cb + 4 * l + j;
        float v = lrelu(fj[j] + bb[jj]);
        v = lrelu(v * ow[jj]);
        sf[wave][4 * l + j] = v;
    }

    float o = 0.f;
    if (l < 32) {
        float h = b1[l];
#pragma unroll 4
        for (int j = 0; j < 256; j++) h += sf[wave][j] * w1[j * 32 + l];
        h = lrelu(h);
        o = h * w2[l];
    }
    o += __shfl_xor(o, 16); o += __shfl_xor(o, 8); o += __shfl_xor(o, 4);
    o += __shfl_xor(o, 2);  o += __shfl_xor(o, 1);
    if (l == 0) outp[t] = o + b2[0];
}

// ---------------------------------------------------------------------------
extern "C" void kernel_launch(void* const* d_in, const int* in_sizes, int n_in,
                              void* d_out, int out_size, void* d_ws, size_t ws_size,
                              hipStream_t stream) {
    const float* x   = (const float*)d_in[0];
    const float* w0  = (const float*)d_in[1];
    const float* b0  = (const float*)d_in[2];
    const float* w1  = (const float*)d_in[3];
    const float* g1  = (const float*)d_in[4];
    const float* be1 = (const float*)d_in[5];
    const float* w2  = (const float*)d_in[6];
    const float* g2  = (const float*)d_in[7];
    const float* be2 = (const float*)d_in[8];
    const float* w3  = (const float*)d_in[9];
    const float* g3  = (const float*)d_in[10];
    const float* be3 = (const float*)d_in[11];
    const float* w4  = (const float*)d_in[12];
    const float* g4  = (const float*)d_in[13];
    const float* be4 = (const float*)d_in[14];
    const float* w5  = (const float*)d_in[15];
    const float* g5  = (const float*)d_in[16];
    const float* be5 = (const float*)d_in[17];
    const float* w6  = (const float*)d_in[18];
    const float* g6  = (const float*)d_in[19];
    const float* be6 = (const float*)d_in[20];
    const float* wg  = (const float*)d_in[21];
    const float* bw  = (const float*)d_in[22];
    const float* bbp = (const float*)d_in[23];
    const float* owp = (const float*)d_in[24];
    const float* cw1 = (const float*)d_in[25];
    const float* cb1 = (const float*)d_in[26];
    const float* cw2 = (const float*)d_in[27];
    const float* cb2 = (const float*)d_in[28];

    char* W = (char*)d_ws;
    float2* ssb = (float2*)W;
    float2* ss1 = ssb;
    float2* ss2 = ssb + 64;
    float2* ss3 = ssb + 192;
    float2* ss4 = ssb + 320;
    float2* ss5 = ssb + 576;
    float2* ss6 = ssb + 832;
    double2* part = (double2*)(W + 16384);

    // Big region: identical to the R7/R9-proven map (max span 100,925,440 B).
    char* BIG = W + 262144;
    float* h0  = (float*)(BIG);               // (4,64,256,256) 64 MiB  [0,64M)
    float* h1  = (float*)(BIG + 67108864);    // (8,64,128,128) 32 MiB  [64M,96M)
    float* h2  = (float*)(BIG);               // (8,128,128,128) 64 MiB [0,64M)
    float* h3p = (float*)(BIG + 67108864);    // (8,128,66,68) 18.4 MB  [64M,81.5M)
    float* h4p = (float*)(BIG);               // (8,256,66,68) 36.8 MB  [0,35.1M)
    float* h5p = (float*)(BIG + 36765696);    // (8,256,66,68)          [35.1,70.1M)
    float* h6  = (float*)(BIG);               // (8,256,64,64) 32 MiB   [0,32M)
    float* tok = (float*)(BIG + 36765696);    // (8,4096,256) 32 MiB    [35.1,67.1M)

    // conv0 + conv1 per batch-half
    for (int half = 0; half < 2; half++) {
        conv0_k<<<dim3(64, 4, 4), 256, 0, stream>>>(
            x + (size_t)half * 4 * 3 * 65536, w0, b0, h0);
        conv4x4_k<8, false><<<dim3(16, 4, 8), 256, 0, stream>>>(
            h0, w1, nullptr, h1 + (size_t)half * 4 * 64 * 16384,
            64, 256, 64, 128, 128, 0);
    }
    stats_k<<<dim3(32, 64), 256, 0, stream>>>(h1, part, 64, 7, 7, 128, 128, 0);
    bnfin_k<<<1, 256, 0, stream>>>(part, 32, 64, 1.0 / 131072.0, g1, be1, ss1);
    // conv2 3x3 (masked+XFORM, 6-row, COG16): h1 raw -> h2 raw
    c3x3_k<16, false><<<dim3(16, 8, 8), 256, 0, stream>>>(
        h1, w2, ss1, h2, 64, 128, 128, 128, 128, 128, 128, 0);
    stats_k<<<dim3(32, 128), 256, 0, stream>>>(h2, part, 128, 7, 7, 128, 128, 0);
    bnfin_k<<<1, 256, 0, stream>>>(part, 32, 128, 1.0 / 131072.0, g2, be2, ss2);
    // conv3 4x4 s2 (masked+XFORM): h2 raw -> h3p raw padded interior
    conv4x4_k<8, true><<<dim3(4, 8, 16), 256, 0, stream>>>(
        h2, w3, ss2, h3p, 128, 128, 128, 66, 68, 1);
    stats_k<<<dim3(32, 128), 256, 0, stream>>>(h3p, part, 128, 6, 6, 66, 68, 1);
    bnfin_k<<<1, 256, 0, stream>>>(part, 32, 128, 1.0 / 32768.0, g3, be3, ss3);
    bnact_k<<<1024, 256, 0, stream>>>(h3p, ss3, 128, 64, 64, 66, 68);
    // conv4 3x3 padded 6-row COG16: h3p -> h4p raw padded interior
    c3x3_k<16, true><<<dim3(4, 8, 16), 256, 0, stream>>>(
        h3p, w4, nullptr, h4p, 128, 256, 64, 66, 68, 66, 68, 1);
    stats_k<<<dim3(32, 256), 256, 0, stream>>>(h4p, part, 256, 6, 6, 66, 68, 1);
    bnfin_k<<<1, 256, 0, stream>>>(part, 32, 256, 1.0 / 32768.0, g4, be4, ss4);
    bnact_k<<<2048, 256, 0, stream>>>(h4p, ss4, 256, 64, 64, 66, 68);
    // conv5 3x3 padded 6-row COG16: h4p -> h5p
    c3x3_k<16, true><<<dim3(4, 8, 16), 256, 0, stream>>>(
        h4p, w5, nullptr, h5p, 256, 256, 64, 66, 68, 66, 68, 1);
    stats_k<<<dim3(32, 256), 256, 0, stream>>>(h5p, part, 256, 6, 6, 66, 68, 1);
    bnfin_k<<<1, 256, 0, stream>>>(part, 32, 256, 1.0 / 32768.0, g5, be5, ss5);
    bnact_k<<<2048, 256, 0, stream>>>(h5p, ss5, 256, 64, 64, 66, 68);
    // conv6 3x3 padded 6-row COG16: h5p -> h6 unpadded raw
    c3x3_k<16, true><<<dim3(4, 8, 16), 256, 0, stream>>>(
        h5p, w6, nullptr, h6, 256, 256, 64, 66, 68, 64, 64, 0);
    stats_k<<<dim3(32, 256), 256, 0, stream>>>(h6, part, 256, 6, 6, 64, 64, 0);
    bnfin_k<<<1, 256, 0, stream>>>(part, 32, 256, 1.0 / 32768.0, g6, be6, ss6);
    // transpose + BN6 + lrelu -> tok
    transp_k<<<dim3(128, 8, 8), 256, 0, stream>>>(h6, ss6, tok);
    // token stage -> out fp32 (8,4096,1)
    token_k<<<8192, 256, 0, stream>>>(tok, wg, bw, bbp, owp, cw1, cb1, cw2, cb2,
                                      (float*)d_out);
}

// Round 11
// 3213.525 us; speedup vs baseline: 1.3237x; 1.3237x over previous
//
#include <hip/hip_runtime.h>

__device__ __forceinline__ float lrelu(float x) { return x >= 0.f ? x : 0.2f * x; }

typedef const __attribute__((address_space(1))) void* gas_ptr;
typedef __attribute__((address_space(3))) void* las_ptr;

// ---------------------------------------------------------------------------
// conv0: fp32 x (4,3,256,256) (half batch), w (64,3,3,3), s1 p1, +bias+lrelu
// -> ACTIVATED fp32 unpadded (4,64,256,256)
// ---------------------------------------------------------------------------
__global__ __launch_bounds__(256) void conv0_k(const float* __restrict__ x,
                                               const float* __restrict__ w,
                                               const float* __restrict__ bias,
                                               float* __restrict__ out) {
    __shared__ float sIn[3][34][34];
    __shared__ float sW[27][16];
    const int H = 256;
    int tid = threadIdx.x, tx = tid & 31, ty = tid >> 5;
    int tX = (blockIdx.x & 7) * 32, tY = (blockIdx.x >> 3) * 32;
    int b = blockIdx.y, cog = blockIdx.z * 16;
    float acc[4][16] = {};
    const float* inB = x + (size_t)b * 3 * H * H;
    for (int idx = tid; idx < 3 * 1156; idx += 256) {
        int ci = idx / 1156, r = idx % 1156, iy = r / 34, ix = r % 34;
        int gy = tY - 1 + iy, gx = tX - 1 + ix;
        float v = 0.f;
        if ((unsigned)gy < 256u && (unsigned)gx < 256u)
            v = inB[(ci * H + gy) * H + gx];
        sIn[ci][iy][ix] = v;
    }
    for (int idx = tid; idx < 27 * 16; idx += 256) {
        int co = idx & 15, rest = idx >> 4;
        sW[rest][co] = w[(cog + co) * 27 + rest];
    }
    __syncthreads();
#pragma unroll
    for (int ci = 0; ci < 3; ci++)
#pragma unroll
        for (int dy = 0; dy < 3; dy++)
#pragma unroll
            for (int dx = 0; dx < 3; dx++) {
                float a0 = sIn[ci][ty + dy][tx + dx];
                float a1 = sIn[ci][ty + 8 + dy][tx + dx];
                float a2 = sIn[ci][ty + 16 + dy][tx + dx];
                float a3 = sIn[ci][ty + 24 + dy][tx + dx];
                const float* wp = sW[ci * 9 + dy * 3 + dx];
#pragma unroll
                for (int co = 0; co < 16; co++) {
                    float wv = wp[co];
                    acc[0][co] += a0 * wv; acc[1][co] += a1 * wv;
                    acc[2][co] += a2 * wv; acc[3][co] += a3 * wv;
                }
            }
    float* outB = out + ((size_t)b * 64 + cog) * H * H;
#pragma unroll
    for (int co = 0; co < 16; co++) {
        float bv = bias[cog + co];
#pragma unroll
        for (int r = 0; r < 4; r++)
            outB[(co * H + (tY + ty + 8 * r)) * H + tX + tx] =
                lrelu(acc[r][co] + bv);
    }
}

// ---------------------------------------------------------------------------
// Unified 3x3 s1 conv, 6-row register reuse, double-buffered LDS.
// PADDED: async global->LDS staging via global_load_lds width=16 (LDS dest
//   is linear in tid => wave-uniform base + lane*16, m104/m108-safe).
//   Issued at top of step into buffer nb (consumed before last barrier).
// !PADDED: R9-proven masked scalar staging + per-channel lrelu(sc*x+sh).
// VGPR notes: R8 proved capping at 64 spills acc (22 GB traffic); R10 proved
// COG=16 (212 VGPR, 2 waves/SIMD) regresses. Sweet spot: COG=8, ~120 VGPR.
// ---------------------------------------------------------------------------
template <int COG, bool PADDED>
__global__ __launch_bounds__(256) void c3x3_k(const float* __restrict__ in,
                                              const float* __restrict__ w,
                                              const float2* __restrict__ ss,
                                              float* __restrict__ out,
                                              int Cin, int Cout, int H,
                                              int Hp, int Wp,
                                              int oHp, int oWp, int oOff) {
    constexpr int RS = PADDED ? 36 : 34;      // LDS row stride (floats)
    constexpr int CI = 34 * RS;               // per-cin LDS floats
    __shared__ float sIn[2][2 * CI];
    __shared__ float sW[2][18 * COG];
    const int tid = threadIdx.x, tx = tid & 31, ty = tid >> 5;  // ty: 8 bands
    const int tpr = H >> 5;
    const int tX = (blockIdx.x % tpr) * 32, tY = (blockIdx.x / tpr) * 32;
    const int b = blockIdx.y, cog = blockIdx.z * COG;
    const int HWin = Hp * Wp;
    const float* inB = in + (size_t)b * Cin * HWin;
    const int wvbase = tid & ~63;             // wave-uniform lane-0 slot

    constexpr int NSTG = PADDED ? 3 : 10;
    int gOff[NSTG]; int lOff[NSTG]; float fm[NSTG]; int cis[NSTG]; bool act[NSTG];
#pragma unroll
    for (int r = 0; r < NSTG; r++) {
        int idx = tid + r * 256;
        if (PADDED) {
            bool a = idx < 612;               // 2 cins x 34 rows x 9 float4
            int ci = idx / 306, rem = idx % 306;
            int row = rem / 9, c4 = rem % 9;
            gOff[r] = a ? (ci * HWin + (tY + row) * Wp + tX + 4 * c4) : 0;
            lOff[r] = (r * 256 + wvbase) * 4; // elem base for async DMA
            act[r] = a; fm[r] = 1.f; cis[r] = ci;
        } else {
            int ci = idx / 1156, rem = idx % 1156;
            int iy = rem / 34, ix = rem % 34;
            int gy = tY - 1 + iy, gx = tX - 1 + ix;
            bool ok = (idx < 2312) && ((unsigned)gy < (unsigned)H) &&
                      ((unsigned)gx < (unsigned)H);
            gOff[r] = ok ? (ci * HWin + gy * Wp + gx) : 0;
            lOff[r] = idx;                    // == ci*CI + iy*RS + ix
            fm[r] = ok ? 1.f : 0.f;
            cis[r] = ci; act[r] = idx < 2312;
        }
    }
    constexpr int NW = (18 * COG + 255) / 256;
    int wgo[NW]; bool wact[NW];
#pragma unroll
    for (int r = 0; r < NW; r++) {
        int widx = tid + r * 256;
        bool a = widx < 18 * COG;
        int co = widx % COG, rest = widx / COG;   // rest = ci*9 + t
        int ci = rest / 9, t = rest % 9;
        wgo[r] = a ? (((cog + co) * Cin + ci) * 9 + t) : 0;
        wact[r] = a;
    }

    float acc[4][COG];
#pragma unroll
    for (int j = 0; j < 4; j++)
#pragma unroll
        for (int c = 0; c < COG; c++) acc[j][c] = 0.f;

    const int steps = Cin >> 1;

    // ---- stage step 0 -> buf 0
    if (PADDED) {
#pragma unroll
        for (int r = 0; r < NSTG; r++)
            if (act[r])
                __builtin_amdgcn_global_load_lds(
                    (gas_ptr)(inB + gOff[r]),
                    (las_ptr)(&sIn[0][lOff[r]]), 16, 0, 0);
#pragma unroll
        for (int r = 0; r < NW; r++)
            if (wact[r])
                __builtin_amdgcn_global_load_lds(
                    (gas_ptr)(w + wgo[r]),
                    (las_ptr)(&sW[0][r * 256 + wvbase]), 4, 0, 0);
    } else {
        float pw[NW];
#pragma unroll
        for (int r = 0; r < NW; r++) pw[r] = w[wgo[r]];
        float pf[NSTG];
#pragma unroll
        for (int r = 0; r < NSTG; r++) pf[r] = inB[gOff[r]];
#pragma unroll
        for (int r = 0; r < NSTG; r++)
            if (act[r]) {
                float2 t = ss[cis[r]];
                float v = t.x * pf[r] + t.y;
                sIn[0][lOff[r]] = (v >= 0.f ? v : 0.2f * v) * fm[r];
            }
#pragma unroll
        for (int r = 0; r < NW; r++)
            if (wact[r]) sW[0][tid + r * 256] = pw[r];
    }
    __syncthreads();

    for (int k = 0; k < steps; k++) {
        const int cur = k & 1;
        const int nb = cur ^ 1;
        const bool more = (k + 1) < steps;
        float pfs[PADDED ? 1 : NSTG];
        float pw[NW]; float2 t0, t1;
        if (more) {
            const int c0n = 2 * (k + 1);
            const float* p = inB + (size_t)c0n * HWin;
            const float* wp2 = w + (size_t)c0n * 9;
            if (PADDED) {
                // async DMA into buffer nb (fully consumed last step)
#pragma unroll
                for (int r = 0; r < NSTG; r++)
                    if (act[r])
                        __builtin_amdgcn_global_load_lds(
                            (gas_ptr)(p + gOff[r]),
                            (las_ptr)(&sIn[nb][lOff[r]]), 16, 0, 0);
#pragma unroll
                for (int r = 0; r < NW; r++)
                    if (wact[r])
                        __builtin_amdgcn_global_load_lds(
                            (gas_ptr)(wp2 + wgo[r]),
                            (las_ptr)(&sW[nb][r * 256 + wvbase]), 4, 0, 0);
            } else {
                t0 = ss[c0n]; t1 = ss[c0n + 1];
#pragma unroll
                for (int r = 0; r < NW; r++) pw[r] = wp2[wgo[r]];
#pragma unroll
                for (int r = 0; r < NSTG; r++) pfs[r] = p[gOff[r]];
            }
        }
        // ---- compute on buf cur (6-row register reuse)
        const float* sI = sIn[cur];
        const float* sw = sW[cur];
#pragma unroll
        for (int ci = 0; ci < 2; ci++)
#pragma unroll
            for (int dx = 0; dx < 3; dx++) {
                const float* bp = sI + ci * CI + (4 * ty) * RS + tx + dx;
                float a[6];
#pragma unroll
                for (int j = 0; j < 6; j++) a[j] = bp[j * RS];
#pragma unroll
                for (int dy = 0; dy < 3; dy++) {
                    const float* wp = sw + (ci * 9 + dy * 3 + dx) * COG;
#pragma unroll
                    for (int c = 0; c < COG; c++) {
                        float wv = wp[c];
                        acc[0][c] += a[0 + dy] * wv;
                        acc[1][c] += a[1 + dy] * wv;
                        acc[2][c] += a[2 + dy] * wv;
                        acc[3][c] += a[3 + dy] * wv;
                    }
                }
            }
        if (more && !PADDED) {
#pragma unroll
            for (int r = 0; r < NSTG; r++)
                if (act[r]) {
                    float2 t = cis[r] ? t1 : t0;
                    float v = t.x * pfs[r] + t.y;
                    sIn[nb][lOff[r]] = (v >= 0.f ? v : 0.2f * v) * fm[r];
                }
#pragma unroll
            for (int r = 0; r < NW; r++)
                if (wact[r]) sW[nb][tid + r * 256] = pw[r];
        }
        __syncthreads();
    }

    float* outB = out + (size_t)(b * Cout + cog) * oHp * oWp;
#pragma unroll
    for (int c = 0; c < COG; c++)
#pragma unroll
        for (int j = 0; j < 4; j++)
            outB[(size_t)c * oHp * oWp +
                 (size_t)(tY + 4 * ty + j + oOff) * oWp + tX + tx + oOff] =
                acc[j][c];
}

// ---------------------------------------------------------------------------
// R5-proven 4x4 s2 p1 conv, masked staging, dbuf; output padded via
// oHp/oWp/oOff. XFORM applies lrelu(scale*x+shift) on load. (conv1, conv3)
// ---------------------------------------------------------------------------
template <int COG, bool XFORM>
__global__ __launch_bounds__(256) void conv4x4_k(const float* __restrict__ in,
                                                 const float* __restrict__ w,
                                                 const float2* __restrict__ ss,
                                                 float* __restrict__ out,
                                                 int Cin, int Hin,
                                                 int Cout, int oHp, int oWp,
                                                 int oOff) {
    __shared__ float sInF[2 * 4356];
    __shared__ float sWF[2 * 16 * COG];
    const int Hout = Hin >> 1;
    const int tid = threadIdx.x, tx = tid & 31, ty = tid >> 5;
    const int tpr = Hout >> 5;
    const int tX = (blockIdx.x % tpr) * 32, tY = (blockIdx.x / tpr) * 32;
    const int b = blockIdx.y, cog = blockIdx.z * COG;
    const int oy = 2 * tY - 1, ox = 2 * tX - 1;
    const int HH = Hin * Hin;
    const float* inB = in + (size_t)b * Cin * HH;

    constexpr int NS = 18;
    int soff[NS]; float fm[NS];
#pragma unroll
    for (int r = 0; r < NS; r++) {
        int idx = tid + r * 256;
        int iy = idx / 66, ix = idx % 66;
        int gy = oy + iy, gx = ox + ix;
        bool ok = (idx < 4356) && ((unsigned)gy < (unsigned)Hin) &&
                  ((unsigned)gx < (unsigned)Hin);
        soff[r] = ok ? (gy * Hin + gx) : 0;
        fm[r] = ok ? 1.f : 0.f;
    }
    constexpr int NW = (16 * COG + 255) / 256;
    int wgo[NW];
#pragma unroll
    for (int r = 0; r < NW; r++) {
        int widx = tid + r * 256;
        int co = widx % COG, t = widx / COG;
        wgo[r] = ((cog + co) * Cin) * 16 + t;
    }

    float acc[4][COG];
#pragma unroll
    for (int r = 0; r < 4; r++)
#pragma unroll
        for (int c = 0; c < COG; c++) acc[r][c] = 0.f;

    {
        float pf[NS]; float pw[NW];
        float2 tt = XFORM ? ss[0] : make_float2(1.f, 0.f);
#pragma unroll
        for (int r = 0; r < NS; r++) pf[r] = inB[soff[r]];
#pragma unroll
        for (int r = 0; r < NW; r++)
            pw[r] = (tid + r * 256 < 16 * COG) ? w[wgo[r]] : 0.f;
#pragma unroll
        for (int r = 0; r < NS; r++)
            if (tid + r * 256 < 4356) {
                float v = pf[r];
                if (XFORM) { v = tt.x * v + tt.y; v = (v >= 0.f ? v : 0.2f * v); }
                sInF[tid + r * 256] = v * fm[r];
            }
#pragma unroll
        for (int r = 0; r < NW; r++)
            if (tid + r * 256 < 16 * COG) sWF[tid + r * 256] = pw[r];
    }
    __syncthreads();

    for (int k = 0; k < Cin; k++) {
        const int cur = k & 1;
        const bool more = (k + 1) < Cin;
        float pf[NS]; float pw[NW]; float2 tt;
        if (more) {
            const int c0n = k + 1;
            const float* p = inB + (size_t)c0n * HH;
            if (XFORM) tt = ss[c0n];
#pragma unroll
            for (int r = 0; r < NS; r++) pf[r] = p[soff[r]];
#pragma unroll
            for (int r = 0; r < NW; r++)
                pw[r] = (tid + r * 256 < 16 * COG) ? w[wgo[r] + c0n * 16] : 0.f;
        }
        const float* sI = sInF + cur * 4356;
        const float* sw = sWF + cur * 16 * COG;
#pragma unroll
        for (int dy = 0; dy < 4; dy++)
#pragma unroll
            for (int dx = 0; dx < 4; dx++) {
                const float* basep = sI + (2 * ty + dy) * 66 + 2 * tx + dx;
                float a0 = basep[0];
                float a1 = basep[16 * 66];
                float a2 = basep[32 * 66];
                float a3 = basep[48 * 66];
                const float* wp = sw + (dy * 4 + dx) * COG;
#pragma unroll
                for (int c = 0; c < COG; c++) {
                    float wv = wp[c];
                    acc[0][c] += a0 * wv; acc[1][c] += a1 * wv;
                    acc[2][c] += a2 * wv; acc[3][c] += a3 * wv;
                }
            }
        if (more) {
            const int nb = (cur ^ 1);
#pragma unroll
            for (int r = 0; r < NS; r++)
                if (tid + r * 256 < 4356) {
                    float v = pf[r];
                    if (XFORM) { v = tt.x * v + tt.y; v = (v >= 0.f ? v : 0.2f * v); }
                    sInF[nb * 4356 + tid + r * 256] = v * fm[r];
                }
#pragma unroll
            for (int r = 0; r < NW; r++)
                if (tid + r * 256 < 16 * COG)
                    sWF[nb * 16 * COG + tid + r * 256] = pw[r];
        }
        __syncthreads();
    }

    float* outB = out + (size_t)(b * Cout + cog) * oHp * oWp;
#pragma unroll
    for (int c = 0; c < COG; c++)
#pragma unroll
        for (int r = 0; r < 4; r++)
            outB[(size_t)c * oHp * oWp +
                 (size_t)(tY + ty + 8 * r + oOff) * oWp + tX + tx + oOff] =
                acc[r][c];
}

// ---------------------------------------------------------------------------
// BN batch stats (FP64 partials). Handles padded interior via Hp/Wp/off.
// ---------------------------------------------------------------------------
__global__ __launch_bounds__(256) void stats_k(const float* __restrict__ x,
                                               double2* __restrict__ part,
                                               int C, int hs, int ws,
                                               int Hp, int Wp, int off) {
    int c = blockIdx.y, s = blockIdx.x, S = gridDim.x;
    int H = 1 << hs, W = 1 << ws;
    int total = 8 << (hs + ws);
    int per = total / S;
    int lo = s * per;
    double sum = 0.0, sq = 0.0;
    for (int i = lo + threadIdx.x; i < lo + per; i += 256) {
        int b = i >> (hs + ws);
        int y = (i >> ws) & (H - 1);
        int xx = i & (W - 1);
        double v = x[((size_t)(b * C + c) * Hp + y + off) * Wp + xx + off];
        sum += v; sq += v * v;
    }
    __shared__ double s1[256], s2[256];
    s1[threadIdx.x] = sum; s2[threadIdx.x] = sq;
    __syncthreads();
    for (int o = 128; o; o >>= 1) {
        if (threadIdx.x < o) {
            s1[threadIdx.x] += s1[threadIdx.x + o];
            s2[threadIdx.x] += s2[threadIdx.x + o];
        }
        __syncthreads();
    }
    if (threadIdx.x == 0) { part[c * S + s].x = s1[0]; part[c * S + s].y = s2[0]; }
}

__global__ void bnfin_k(const double2* __restrict__ part, int S, int C, double invN,
                        const float* __restrict__ g, const float* __restrict__ bb,
                        float2* __restrict__ ss) {
    int c = threadIdx.x;
    if (c >= C) return;
    double sum = 0.0, sq = 0.0;
    for (int s = 0; s < S; s++) { double2 p = part[c * S + s]; sum += p.x; sq += p.y; }
    double m = sum * invN;
    double v = sq * invN - m * m;
    double sc = (double)g[c] / sqrt(v + 1e-5);
    ss[c] = make_float2((float)sc, (float)((double)bb[c] - m * sc));
}

// ---------------------------------------------------------------------------
// bnact: zero padded border + transform interior in place lrelu(sc*x+sh).
// ---------------------------------------------------------------------------
__global__ __launch_bounds__(256) void bnact_k(float* __restrict__ p,
                                               const float2* __restrict__ ss,
                                               int C, int H, int W,
                                               int Hp, int Wp) {
    int pc = blockIdx.x;
    int c = pc & (C - 1);
    float2 t = ss[c];
    float* pl = p + (size_t)pc * Hp * Wp;
    int n = Hp * Wp;
    for (int i = threadIdx.x; i < n; i += 256) {
        int y = i / Wp, x = i - y * Wp;
        bool inter = (y >= 1) && (y <= H) && (x >= 1) && (x <= W);
        if (!inter) pl[i] = 0.f;
        else { float v = pl[i]; pl[i] = lrelu(t.x * v + t.y); }
    }
}

// ---------------------------------------------------------------------------
// h6 raw (8,256,64,64) + BN6+lrelu -> tok (8,4096,256)
// ---------------------------------------------------------------------------
__global__ __launch_bounds__(256) void transp_k(const float* __restrict__ h6,
                                                const float2* __restrict__ ss,
                                                float* __restrict__ tok) {
    __shared__ float sT[32][33];
    int tx = threadIdx.x & 31, ty = threadIdx.x >> 5;
    int n0 = blockIdx.x * 32, d0 = blockIdx.y * 32, b = blockIdx.z;
    const float* hb = h6 + ((size_t)b * 256 + d0) * 4096 + n0;
#pragma unroll
    for (int r = 0; r < 4; r++) {
        int d = ty + 8 * r;
        float2 t = ss[d0 + d];
        sT[d][tx] = lrelu(t.x * hb[d * 4096 + tx] + t.y);
    }
    __syncthreads();
    float* tb = tok + ((size_t)b * 4096 + n0) * 256 + d0;
#pragma unroll
    for (int r = 0; r < 4; r++) {
        int n = ty + 8 * r;
        tb[n * 256 + tx] = sT[tx][n];
    }
}

// ---------------------------------------------------------------------------
// Token stage: gating argmax, selected-expert body slice, ortho, cls MLP.
// ---------------------------------------------------------------------------
__global__ __launch_bounds__(256) void token_k(const float* __restrict__ tok,
                                               const float* __restrict__ wg,
                                               const float* __restrict__ bw,
                                               const float* __restrict__ bb,
                                               const float* __restrict__ ow,
                                               const float* __restrict__ w1,
                                               const float* __restrict__ b1,
                                               const float* __restrict__ w2,
                                               const float* __restrict__ b2,
                                               float* __restrict__ outp) {
    __shared__ float sf[4][256];
    const int tid = threadIdx.x, wave = tid >> 6, l = tid & 63;
    const int t = blockIdx.x * 4 + wave;
    const float4 tv = reinterpret_cast<const float4*>(tok + (size_t)t * 256)[l];
    sf[wave][4 * l + 0] = tv.x; sf[wave][4 * l + 1] = tv.y;
    sf[wave][4 * l + 2] = tv.z; sf[wave][4 * l + 3] = tv.w;

    float lg[12];
#pragma unroll
    for (int e = 0; e < 12; e++) lg[e] = 0.f;
    const float tj[4] = {tv.x, tv.y, tv.z, tv.w};
#pragma unroll
    for (int j = 0; j < 4; j++) {
        const float* wr = wg + (4 * l + j) * 12;
#pragma unroll
        for (int e = 0; e < 12; e++) lg[e] += tj[j] * wr[e];
    }
#pragma unroll
    for (int off = 32; off > 0; off >>= 1) {
#pragma unroll
        for (int e = 0; e < 12; e++) lg[e] += __shfl_xor(lg[e], off);
    }
    int idx = 0; float best = lg[0];
#pragma unroll
    for (int e = 1; e < 12; e++)
        if (lg[e] > best) { best = lg[e]; idx = e; }
    const int cb = idx * 256;

    float f0 = 0.f, f1 = 0.f, f2 = 0.f, f3 = 0.f;
    const float* bwp = bw + cb + 4 * l;
#pragma unroll 4
    for (int d = 0; d < 256; d++) {
        const float td = sf[wave][d];
        const float4 wv = *reinterpret_cast<const float4*>(bwp + (size_t)d * 3072);
        f0 += td * wv.x; f1 += td * wv.y;
        f2 += td * wv.z; f3 += td * wv.w;
    }
    float fj[4] = {f0, f1, f2, f3};
#pragma unroll
    for (int j = 0; j < 4; j++) {
        int jj = cb + 4 * l + j;
        float v = lrelu(fj[j] + bb[jj]);
        v = lrelu(v * ow[jj]);
        sf[wave][4 * l + j] = v;
    }

    float o = 0.f;
    if (l < 32) {
        float h = b1[l];
#pragma unroll 4
        for (int j = 0; j < 256; j++) h += sf[wave][j] * w1[j * 32 + l];
        h = lrelu(h);
        o = h * w2[l];
    }
    o += __shfl_xor(o, 16); o += __shfl_xor(o, 8); o += __shfl_xor(o, 4);
    o += __shfl_xor(o, 2);  o += __shfl_xor(o, 1);
    if (l == 0) outp[t] = o + b2[0];
}

// ---------------------------------------------------------------------------
extern "C" void kernel_launch(void* const* d_in, const int* in_sizes, int n_in,
                              void* d_out, int out_size, void* d_ws, size_t ws_size,
                              hipStream_t stream) {
    const float* x   = (const float*)d_in[0];
    const float* w0  = (const float*)d_in[1];
    const float* b0  = (const float*)d_in[2];
    const float* w1  = (const float*)d_in[3];
    const float* g1  = (const float*)d_in[4];
    const float* be1 = (const float*)d_in[5];
    const float* w2  = (const float*)d_in[6];
    const float* g2  = (const float*)d_in[7];
    const float* be2 = (const float*)d_in[8];
    const float* w3  = (const float*)d_in[9];
    const float* g3  = (const float*)d_in[10];
    const float* be3 = (const float*)d_in[11];
    const float* w4  = (const float*)d_in[12];
    const float* g4  = (const float*)d_in[13];
    const float* be4 = (const float*)d_in[14];
    const float* w5  = (const float*)d_in[15];
    const float* g5  = (const float*)d_in[16];
    const float* be5 = (const float*)d_in[17];
    const float* w6  = (const float*)d_in[18];
    const float* g6  = (const float*)d_in[19];
    const float* be6 = (const float*)d_in[20];
    const float* wg  = (const float*)d_in[21];
    const float* bw  = (const float*)d_in[22];
    const float* bbp = (const float*)d_in[23];
    const float* owp = (const float*)d_in[24];
    const float* cw1 = (const float*)d_in[25];
    const float* cb1 = (const float*)d_in[26];
    const float* cw2 = (const float*)d_in[27];
    const float* cb2 = (const float*)d_in[28];

    char* W = (char*)d_ws;
    float2* ssb = (float2*)W;
    float2* ss1 = ssb;
    float2* ss2 = ssb + 64;
    float2* ss3 = ssb + 192;
    float2* ss4 = ssb + 320;
    float2* ss5 = ssb + 576;
    float2* ss6 = ssb + 832;
    double2* part = (double2*)(W + 16384);

    // Big region: identical to the R7/R9-proven map (max span 100,925,440 B).
    char* BIG = W + 262144;
    float* h0  = (float*)(BIG);               // (4,64,256,256) 64 MiB  [0,64M)
    float* h1  = (float*)(BIG + 67108864);    // (8,64,128,128) 32 MiB  [64M,96M)
    float* h2  = (float*)(BIG);               // (8,128,128,128) 64 MiB [0,64M)
    float* h3p = (float*)(BIG + 67108864);    // (8,128,66,68) 18.4 MB  [64M,81.5M)
    float* h4p = (float*)(BIG);               // (8,256,66,68) 36.8 MB  [0,35.1M)
    float* h5p = (float*)(BIG + 36765696);    // (8,256,66,68)          [35.1,70.1M)
    float* h6  = (float*)(BIG);               // (8,256,64,64) 32 MiB   [0,32M)
    float* tok = (float*)(BIG + 36765696);    // (8,4096,256) 32 MiB    [35.1,67.1M)

    // conv0 + conv1 per batch-half
    for (int half = 0; half < 2; half++) {
        conv0_k<<<dim3(64, 4, 4), 256, 0, stream>>>(
            x + (size_t)half * 4 * 3 * 65536, w0, b0, h0);
        conv4x4_k<8, false><<<dim3(16, 4, 8), 256, 0, stream>>>(
            h0, w1, nullptr, h1 + (size_t)half * 4 * 64 * 16384,
            64, 256, 64, 128, 128, 0);
    }
    stats_k<<<dim3(32, 64), 256, 0, stream>>>(h1, part, 64, 7, 7, 128, 128, 0);
    bnfin_k<<<1, 256, 0, stream>>>(part, 32, 64, 1.0 / 131072.0, g1, be1, ss1);
    // conv2 3x3 (masked+XFORM, 6-row, COG8): h1 raw -> h2 raw
    c3x3_k<8, false><<<dim3(16, 8, 16), 256, 0, stream>>>(
        h1, w2, ss1, h2, 64, 128, 128, 128, 128, 128, 128, 0);
    stats_k<<<dim3(32, 128), 256, 0, stream>>>(h2, part, 128, 7, 7, 128, 128, 0);
    bnfin_k<<<1, 256, 0, stream>>>(part, 32, 128, 1.0 / 131072.0, g2, be2, ss2);
    // conv3 4x4 s2 (masked+XFORM): h2 raw -> h3p raw padded interior
    conv4x4_k<8, true><<<dim3(4, 8, 16), 256, 0, stream>>>(
        h2, w3, ss2, h3p, 128, 128, 128, 66, 68, 1);
    stats_k<<<dim3(32, 128), 256, 0, stream>>>(h3p, part, 128, 6, 6, 66, 68, 1);
    bnfin_k<<<1, 256, 0, stream>>>(part, 32, 128, 1.0 / 32768.0, g3, be3, ss3);
    bnact_k<<<1024, 256, 0, stream>>>(h3p, ss3, 128, 64, 64, 66, 68);
    // conv4 3x3 padded 6-row COG8 async: h3p -> h4p raw padded interior
    c3x3_k<8, true><<<dim3(4, 8, 32), 256, 0, stream>>>(
        h3p, w4, nullptr, h4p, 128, 256, 64, 66, 68, 66, 68, 1);
    stats_k<<<dim3(32, 256), 256, 0, stream>>>(h4p, part, 256, 6, 6, 66, 68, 1);
    bnfin_k<<<1, 256, 0, stream>>>(part, 32, 256, 1.0 / 32768.0, g4, be4, ss4);
    bnact_k<<<2048, 256, 0, stream>>>(h4p, ss4, 256, 64, 64, 66, 68);
    // conv5 3x3 padded 6-row COG8 async: h4p -> h5p
    c3x3_k<8, true><<<dim3(4, 8, 32), 256, 0, stream>>>(
        h4p, w5, nullptr, h5p, 256, 256, 64, 66, 68, 66, 68, 1);
    stats_k<<<dim3(32, 256), 256, 0, stream>>>(h5p, part, 256, 6, 6, 66, 68, 1);
    bnfin_k<<<1, 256, 0, stream>>>(part, 32, 256, 1.0 / 32768.0, g5, be5, ss5);
    bnact_k<<<2048, 256, 0, stream>>>(h5p, ss5, 256, 64, 64, 66, 68);
    // conv6 3x3 padded 6-row COG8 async: h5p -> h6 unpadded raw
    c3x3_k<8, true><<<dim3(4, 8, 32), 256, 0, stream>>>(
        h5p, w6, nullptr, h6, 256, 256, 64, 66, 68, 64, 64, 0);
    stats_k<<<dim3(32, 256), 256, 0, stream>>>(h6, part, 256, 6, 6, 64, 64, 0);
    bnfin_k<<<1, 256, 0, stream>>>(part, 32, 256, 1.0 / 32768.0, g6, be6, ss6);
    // transpose + BN6 + lrelu -> tok
    transp_k<<<dim3(128, 8, 8), 256, 0, stream>>>(h6, ss6, tok);
    // token stage -> out fp32 (8,4096,1)
    token_k<<<8192, 256, 0, stream>>>(tok, wg, bw, bbp, owp, cw1, cb1, cw2, cb2,
                                      (float*)d_out);
}

// Round 12
// 2799.017 us; speedup vs baseline: 1.5197x; 1.1481x over previous
//
#include <hip/hip_runtime.h>

__device__ __forceinline__ float lrelu(float x) { return x >= 0.f ? x : 0.2f * x; }

typedef const __attribute__((address_space(1))) void* gas_ptr;
typedef __attribute__((address_space(3))) void* las_ptr;

// ---------------------------------------------------------------------------
// conv0: fp32 x (4,3,256,256) (half batch), w (64,3,3,3), s1 p1, +bias+lrelu
// -> ACTIVATED fp32 PADDED h0p (4,64,258,260), interior at (1,1)
// ---------------------------------------------------------------------------
__global__ __launch_bounds__(256) void conv0_k(const float* __restrict__ x,
                                               const float* __restrict__ w,
                                               const float* __restrict__ bias,
                                               float* __restrict__ out) {
    __shared__ float sIn[3][34][34];
    __shared__ float sW[27][16];
    const int H = 256;
    int tid = threadIdx.x, tx = tid & 31, ty = tid >> 5;
    int tX = (blockIdx.x & 7) * 32, tY = (blockIdx.x >> 3) * 32;
    int b = blockIdx.y, cog = blockIdx.z * 16;
    float acc[4][16] = {};
    const float* inB = x + (size_t)b * 3 * H * H;
    for (int idx = tid; idx < 3 * 1156; idx += 256) {
        int ci = idx / 1156, r = idx % 1156, iy = r / 34, ix = r % 34;
        int gy = tY - 1 + iy, gx = tX - 1 + ix;
        float v = 0.f;
        if ((unsigned)gy < 256u && (unsigned)gx < 256u)
            v = inB[(ci * H + gy) * H + gx];
        sIn[ci][iy][ix] = v;
    }
    for (int idx = tid; idx < 27 * 16; idx += 256) {
        int co = idx & 15, rest = idx >> 4;
        sW[rest][co] = w[(cog + co) * 27 + rest];
    }
    __syncthreads();
#pragma unroll
    for (int ci = 0; ci < 3; ci++)
#pragma unroll
        for (int dy = 0; dy < 3; dy++)
#pragma unroll
            for (int dx = 0; dx < 3; dx++) {
                float a0 = sIn[ci][ty + dy][tx + dx];
                float a1 = sIn[ci][ty + 8 + dy][tx + dx];
                float a2 = sIn[ci][ty + 16 + dy][tx + dx];
                float a3 = sIn[ci][ty + 24 + dy][tx + dx];
                const float* wp = sW[ci * 9 + dy * 3 + dx];
#pragma unroll
                for (int co = 0; co < 16; co++) {
                    float wv = wp[co];
                    acc[0][co] += a0 * wv; acc[1][co] += a1 * wv;
                    acc[2][co] += a2 * wv; acc[3][co] += a3 * wv;
                }
            }
    float* outB = out + (size_t)(b * 64 + cog) * 67080;   // 258*260
#pragma unroll
    for (int co = 0; co < 16; co++) {
        float bv = bias[cog + co];
#pragma unroll
        for (int r = 0; r < 4; r++)
            outB[(size_t)co * 67080 + (size_t)(tY + ty + 8 * r + 1) * 260 +
                 tX + tx + 1] = lrelu(acc[r][co] + bv);
    }
}

// ---------------------------------------------------------------------------
// Async padded 4x4 s2 conv (conv1, conv3). Input ACTIVATED padded (Hp,Wp),
// interior at (1,1), borders zero, Wp%4==0, tiles 32x32 out / 66x68-stage.
// Pure global_load_lds staging (LDS dest linear in tid: wave-uniform base +
// lane*16 — the R11-proven pattern, incl. partial-wave predication).
// ---------------------------------------------------------------------------
template <int COG>
__global__ __launch_bounds__(256) void c4x4p_k(const float* __restrict__ in,
                                               const float* __restrict__ w,
                                               float* __restrict__ out,
                                               int Cin, int Cout, int Hin,
                                               int Hp, int Wp,
                                               int oHp, int oWp, int oOff) {
    __shared__ float sIn[2][4488];            // 66 rows x 68 cols
    __shared__ float sW[2][16 * COG];
    const int Hout = Hin >> 1;
    const int tid = threadIdx.x, tx = tid & 31, ty = tid >> 5;
    const int tpr = Hout >> 5;
    const int tX = (blockIdx.x % tpr) * 32, tY = (blockIdx.x / tpr) * 32;
    const int b = blockIdx.y, cog = blockIdx.z * COG;
    const int HWin = Hp * Wp;
    const float* inB = in + (size_t)b * Cin * HWin;
    const int wvbase = tid & ~63;

    int gOff[5]; int lOff[5]; bool act[5];
#pragma unroll
    for (int r = 0; r < 5; r++) {
        int idx = tid + r * 256;
        bool a = idx < 1122;                  // 66 rows x 17 float4
        int row = idx / 17, c4 = idx % 17;
        gOff[r] = a ? ((2 * tY + row) * Wp + 2 * tX + 4 * c4) : 0;
        lOff[r] = (r * 256 + wvbase) * 4;     // element base for DMA
        act[r] = a;
    }
    const int wco = tid % COG, wt = tid / COG;
    const int wgo = ((cog + wco) * Cin) * 16 + wt;   // LDS slot tid = wt*COG+wco
    const bool wact = tid < 16 * COG;

    float acc[4][COG];
#pragma unroll
    for (int j = 0; j < 4; j++)
#pragma unroll
        for (int c = 0; c < COG; c++) acc[j][c] = 0.f;

    // stage step 0 -> buf 0
#pragma unroll
    for (int r = 0; r < 5; r++)
        if (act[r])
            __builtin_amdgcn_global_load_lds((gas_ptr)(inB + gOff[r]),
                                             (las_ptr)(&sIn[0][lOff[r]]), 16, 0, 0);
    if (wact)
        __builtin_amdgcn_global_load_lds((gas_ptr)(w + wgo),
                                         (las_ptr)(&sW[0][wvbase]), 4, 0, 0);
    __syncthreads();

    for (int k = 0; k < Cin; k++) {
        const int cur = k & 1, nb = cur ^ 1;
        const bool more = (k + 1) < Cin;
        if (more) {
            const float* p = inB + (size_t)(k + 1) * HWin;
#pragma unroll
            for (int r = 0; r < 5; r++)
                if (act[r])
                    __builtin_amdgcn_global_load_lds(
                        (gas_ptr)(p + gOff[r]),
                        (las_ptr)(&sIn[nb][lOff[r]]), 16, 0, 0);
            if (wact)
                __builtin_amdgcn_global_load_lds(
                    (gas_ptr)(w + wgo + (k + 1) * 16),
                    (las_ptr)(&sW[nb][wvbase]), 4, 0, 0);
        }
        const float* sI = sIn[cur];
        const float* sw = sW[cur];
#pragma unroll
        for (int dy = 0; dy < 4; dy++)
#pragma unroll
            for (int dx = 0; dx < 4; dx++) {
                const float* bp = sI + (2 * ty + dy) * 68 + 2 * tx + dx;
                float a0 = bp[0];
                float a1 = bp[16 * 68];
                float a2 = bp[32 * 68];
                float a3 = bp[48 * 68];
                const float* wp = sw + (dy * 4 + dx) * COG;
#pragma unroll
                for (int c = 0; c < COG; c++) {
                    float wv = wp[c];
                    acc[0][c] += a0 * wv; acc[1][c] += a1 * wv;
                    acc[2][c] += a2 * wv; acc[3][c] += a3 * wv;
                }
            }
        __syncthreads();
    }

    float* outB = out + (size_t)(b * Cout + cog) * oHp * oWp;
#pragma unroll
    for (int c = 0; c < COG; c++)
#pragma unroll
        for (int r = 0; r < 4; r++)
            outB[(size_t)c * oHp * oWp +
                 (size_t)(tY + ty + 8 * r + oOff) * oWp + tX + tx + oOff] =
                acc[r][c];
}

// ---------------------------------------------------------------------------
// Unified 3x3 s1 conv, 6-row register reuse, double-buffered LDS.
// PADDED: async global->LDS staging (R11-proven). !PADDED: masked scalar
// staging + per-channel lrelu(sc*x+sh). Output padded via oHp/oWp/oOff.
// VGPR notes: R8 (cap 64 -> spill) and R10 (COG16 -> 2 waves/SIMD) both
// regressed; COG=8 with async staging (~56 VGPR) is the sweet spot.
// ---------------------------------------------------------------------------
template <int COG, bool PADDED>
__global__ __launch_bounds__(256) void c3x3_k(const float* __restrict__ in,
                                              const float* __restrict__ w,
                                              const float2* __restrict__ ss,
                                              float* __restrict__ out,
                                              int Cin, int Cout, int H,
                                              int Hp, int Wp,
                                              int oHp, int oWp, int oOff) {
    constexpr int RS = PADDED ? 36 : 34;
    constexpr int CI = 34 * RS;
    __shared__ float sIn[2][2 * CI];
    __shared__ float sW[2][18 * COG];
    const int tid = threadIdx.x, tx = tid & 31, ty = tid >> 5;
    const int tpr = H >> 5;
    const int tX = (blockIdx.x % tpr) * 32, tY = (blockIdx.x / tpr) * 32;
    const int b = blockIdx.y, cog = blockIdx.z * COG;
    const int HWin = Hp * Wp;
    const float* inB = in + (size_t)b * Cin * HWin;
    const int wvbase = tid & ~63;

    constexpr int NSTG = PADDED ? 3 : 10;
    int gOff[NSTG]; int lOff[NSTG]; float fm[NSTG]; int cis[NSTG]; bool act[NSTG];
#pragma unroll
    for (int r = 0; r < NSTG; r++) {
        int idx = tid + r * 256;
        if (PADDED) {
            bool a = idx < 612;               // 2 cins x 34 rows x 9 float4
            int ci = idx / 306, rem = idx % 306;
            int row = rem / 9, c4 = rem % 9;
            gOff[r] = a ? (ci * HWin + (tY + row) * Wp + tX + 4 * c4) : 0;
            lOff[r] = (r * 256 + wvbase) * 4;
            act[r] = a; fm[r] = 1.f; cis[r] = ci;
        } else {
            int ci = idx / 1156, rem = idx % 1156;
            int iy = rem / 34, ix = rem % 34;
            int gy = tY - 1 + iy, gx = tX - 1 + ix;
            bool ok = (idx < 2312) && ((unsigned)gy < (unsigned)H) &&
                      ((unsigned)gx < (unsigned)H);
            gOff[r] = ok ? (ci * HWin + gy * Wp + gx) : 0;
            lOff[r] = idx;
            fm[r] = ok ? 1.f : 0.f;
            cis[r] = ci; act[r] = idx < 2312;
        }
    }
    constexpr int NW = (18 * COG + 255) / 256;
    int wgo[NW]; bool wact[NW];
#pragma unroll
    for (int r = 0; r < NW; r++) {
        int widx = tid + r * 256;
        bool a = widx < 18 * COG;
        int co = widx % COG, rest = widx / COG;
        int ci = rest / 9, t = rest % 9;
        wgo[r] = a ? (((cog + co) * Cin + ci) * 9 + t) : 0;
        wact[r] = a;
    }

    float acc[4][COG];
#pragma unroll
    for (int j = 0; j < 4; j++)
#pragma unroll
        for (int c = 0; c < COG; c++) acc[j][c] = 0.f;

    const int steps = Cin >> 1;

    if (PADDED) {
#pragma unroll
        for (int r = 0; r < NSTG; r++)
            if (act[r])
                __builtin_amdgcn_global_load_lds(
                    (gas_ptr)(inB + gOff[r]),
                    (las_ptr)(&sIn[0][lOff[r]]), 16, 0, 0);
#pragma unroll
        for (int r = 0; r < NW; r++)
            if (wact[r])
                __builtin_amdgcn_global_load_lds(
                    (gas_ptr)(w + wgo[r]),
                    (las_ptr)(&sW[0][r * 256 + wvbase]), 4, 0, 0);
    } else {
        float pw[NW];
#pragma unroll
        for (int r = 0; r < NW; r++) pw[r] = w[wgo[r]];
        float pf[NSTG];
#pragma unroll
        for (int r = 0; r < NSTG; r++) pf[r] = inB[gOff[r]];
#pragma unroll
        for (int r = 0; r < NSTG; r++)
            if (act[r]) {
                float2 t = ss[cis[r]];
                float v = t.x * pf[r] + t.y;
                sIn[0][lOff[r]] = (v >= 0.f ? v : 0.2f * v) * fm[r];
            }
#pragma unroll
        for (int r = 0; r < NW; r++)
            if (wact[r]) sW[0][tid + r * 256] = pw[r];
    }
    __syncthreads();

    for (int k = 0; k < steps; k++) {
        const int cur = k & 1;
        const int nb = cur ^ 1;
        const bool more = (k + 1) < steps;
        float pfs[PADDED ? 1 : NSTG];
        float pw[NW]; float2 t0, t1;
        if (more) {
            const int c0n = 2 * (k + 1);
            const float* p = inB + (size_t)c0n * HWin;
            const float* wp2 = w + (size_t)c0n * 9;
            if (PADDED) {
#pragma unroll
                for (int r = 0; r < NSTG; r++)
                    if (act[r])
                        __builtin_amdgcn_global_load_lds(
                            (gas_ptr)(p + gOff[r]),
                            (las_ptr)(&sIn[nb][lOff[r]]), 16, 0, 0);
#pragma unroll
                for (int r = 0; r < NW; r++)
                    if (wact[r])
                        __builtin_amdgcn_global_load_lds(
                            (gas_ptr)(wp2 + wgo[r]),
                            (las_ptr)(&sW[nb][r * 256 + wvbase]), 4, 0, 0);
            } else {
                t0 = ss[c0n]; t1 = ss[c0n + 1];
#pragma unroll
                for (int r = 0; r < NW; r++) pw[r] = wp2[wgo[r]];
#pragma unroll
                for (int r = 0; r < NSTG; r++) pfs[r] = p[gOff[r]];
            }
        }
        const float* sI = sIn[cur];
        const float* sw = sW[cur];
#pragma unroll
        for (int ci = 0; ci < 2; ci++)
#pragma unroll
            for (int dx = 0; dx < 3; dx++) {
                const float* bp = sI + ci * CI + (4 * ty) * RS + tx + dx;
                float a[6];
#pragma unroll
                for (int j = 0; j < 6; j++) a[j] = bp[j * RS];
#pragma unroll
                for (int dy = 0; dy < 3; dy++) {
                    const float* wp = sw + (ci * 9 + dy * 3 + dx) * COG;
#pragma unroll
                    for (int c = 0; c < COG; c++) {
                        float wv = wp[c];
                        acc[0][c] += a[0 + dy] * wv;
                        acc[1][c] += a[1 + dy] * wv;
                        acc[2][c] += a[2 + dy] * wv;
                        acc[3][c] += a[3 + dy] * wv;
                    }
                }
            }
        if (more && !PADDED) {
#pragma unroll
            for (int r = 0; r < NSTG; r++)
                if (act[r]) {
                    float2 t = cis[r] ? t1 : t0;
                    float v = t.x * pfs[r] + t.y;
                    sIn[nb][lOff[r]] = (v >= 0.f ? v : 0.2f * v) * fm[r];
                }
#pragma unroll
            for (int r = 0; r < NW; r++)
                if (wact[r]) sW[nb][tid + r * 256] = pw[r];
        }
        __syncthreads();
    }

    float* outB = out + (size_t)(b * Cout + cog) * oHp * oWp;
#pragma unroll
    for (int c = 0; c < COG; c++)
#pragma unroll
        for (int j = 0; j < 4; j++)
            outB[(size_t)c * oHp * oWp +
                 (size_t)(tY + 4 * ty + j + oOff) * oWp + tX + tx + oOff] =
                acc[j][c];
}

// ---------------------------------------------------------------------------
// BN batch stats (FP64 partials). Handles padded interior via Hp/Wp/off.
// ---------------------------------------------------------------------------
__global__ __launch_bounds__(256) void stats_k(const float* __restrict__ x,
                                               double2* __restrict__ part,
                                               int C, int hs, int ws,
                                               int Hp, int Wp, int off) {
    int c = blockIdx.y, s = blockIdx.x, S = gridDim.x;
    int H = 1 << hs, W = 1 << ws;
    int total = 8 << (hs + ws);
    int per = total / S;
    int lo = s * per;
    double sum = 0.0, sq = 0.0;
    for (int i = lo + threadIdx.x; i < lo + per; i += 256) {
        int b = i >> (hs + ws);
        int y = (i >> ws) & (H - 1);
        int xx = i & (W - 1);
        double v = x[((size_t)(b * C + c) * Hp + y + off) * Wp + xx + off];
        sum += v; sq += v * v;
    }
    __shared__ double s1[256], s2[256];
    s1[threadIdx.x] = sum; s2[threadIdx.x] = sq;
    __syncthreads();
    for (int o = 128; o; o >>= 1) {
        if (threadIdx.x < o) {
            s1[threadIdx.x] += s1[threadIdx.x + o];
            s2[threadIdx.x] += s2[threadIdx.x + o];
        }
        __syncthreads();
    }
    if (threadIdx.x == 0) { part[c * S + s].x = s1[0]; part[c * S + s].y = s2[0]; }
}

__global__ void bnfin_k(const double2* __restrict__ part, int S, int C, double invN,
                        const float* __restrict__ g, const float* __restrict__ bb,
                        float2* __restrict__ ss) {
    int c = threadIdx.x;
    if (c >= C) return;
    double sum = 0.0, sq = 0.0;
    for (int s = 0; s < S; s++) { double2 p = part[c * S + s]; sum += p.x; sq += p.y; }
    double m = sum * invN;
    double v = sq * invN - m * m;
    double sc = (double)g[c] / sqrt(v + 1e-5);
    ss[c] = make_float2((float)sc, (float)((double)bb[c] - m * sc));
}

// ---------------------------------------------------------------------------
// bnact: zero padded border; if ss != nullptr also transform interior with
// lrelu(sc*x+sh) in place. One block per (b,c) plane, C power of two.
// ---------------------------------------------------------------------------
__global__ __launch_bounds__(256) void bnact_k(float* __restrict__ p,
                                               const float2* __restrict__ ss,
                                               int C, int H, int W,
                                               int Hp, int Wp) {
    int pc = blockIdx.x;
    int c = pc & (C - 1);
    float2 t = ss ? ss[c] : make_float2(1.f, 0.f);
    bool xf = (ss != nullptr);
    float* pl = p + (size_t)pc * Hp * Wp;
    int n = Hp * Wp;
    for (int i = threadIdx.x; i < n; i += 256) {
        int y = i / Wp, x = i - y * Wp;
        bool inter = (y >= 1) && (y <= H) && (x >= 1) && (x <= W);
        if (!inter) pl[i] = 0.f;
        else if (xf) { float v = pl[i]; pl[i] = lrelu(t.x * v + t.y); }
    }
}

// ---------------------------------------------------------------------------
// h6 raw (8,256,64,64) + BN6+lrelu -> tok (8,4096,256)
// ---------------------------------------------------------------------------
__global__ __launch_bounds__(256) void transp_k(const float* __restrict__ h6,
                                                const float2* __restrict__ ss,
                                                float* __restrict__ tok) {
    __shared__ float sT[32][33];
    int tx = threadIdx.x & 31, ty = threadIdx.x >> 5;
    int n0 = blockIdx.x * 32, d0 = blockIdx.y * 32, b = blockIdx.z;
    const float* hb = h6 + ((size_t)b * 256 + d0) * 4096 + n0;
#pragma unroll
    for (int r = 0; r < 4; r++) {
        int d = ty + 8 * r;
        float2 t = ss[d0 + d];
        sT[d][tx] = lrelu(t.x * hb[d * 4096 + tx] + t.y);
    }
    __syncthreads();
    float* tb = tok + ((size_t)b * 4096 + n0) * 256 + d0;
#pragma unroll
    for (int r = 0; r < 4; r++) {
        int n = ty + 8 * r;
        tb[n * 256 + tx] = sT[tx][n];
    }
}

// ---------------------------------------------------------------------------
// Token stage: gating argmax, selected-expert body slice, ortho, cls MLP.
// ---------------------------------------------------------------------------
__global__ __launch_bounds__(256) void token_k(const float* __restrict__ tok,
                                               const float* __restrict__ wg,
                                               const float* __restrict__ bw,
                                               const float* __restrict__ bb,
                                               const float* __restrict__ ow,
                                               const float* __restrict__ w1,
                                               const float* __restrict__ b1,
                                               const float* __restrict__ w2,
                                               const float* __restrict__ b2,
                                               float* __restrict__ outp) {
    __shared__ float sf[4][256];
    const int tid = threadIdx.x, wave = tid >> 6, l = tid & 63;
    const int t = blockIdx.x * 4 + wave;
    const float4 tv = reinterpret_cast<const float4*>(tok + (size_t)t * 256)[l];
    sf[wave][4 * l + 0] = tv.x; sf[wave][4 * l + 1] = tv.y;
    sf[wave][4 * l + 2] = tv.z; sf[wave][4 * l + 3] = tv.w;

    float lg[12];
#pragma unroll
    for (int e = 0; e < 12; e++) lg[e] = 0.f;
    const float tj[4] = {tv.x, tv.y, tv.z, tv.w};
#pragma unroll
    for (int j = 0; j < 4; j++) {
        const float* wr = wg + (4 * l + j) * 12;
#pragma unroll
        for (int e = 0; e < 12; e++) lg[e] += tj[j] * wr[e];
    }
#pragma unroll
    for (int off = 32; off > 0; off >>= 1) {
#pragma unroll
        for (int e = 0; e < 12; e++) lg[e] += __shfl_xor(lg[e], off);
    }
    int idx = 0; float best = lg[0];
#pragma unroll
    for (int e = 1; e < 12; e++)
        if (lg[e] > best) { best = lg[e]; idx = e; }
    const int cb = idx * 256;

    float f0 = 0.f, f1 = 0.f, f2 = 0.f, f3 = 0.f;
    const float* bwp = bw + cb + 4 * l;
#pragma unroll 4
    for (int d = 0; d < 256; d++) {
        const float td = sf[wave][d];
        const float4 wv = *reinterpret_cast<const float4*>(bwp + (size_t)d * 3072);
        f0 += td * wv.x; f1 += td * wv.y;
        f2 += td * wv.z; f3 += td * wv.w;
    }
    float fj[4] = {f0, f1, f2, f3};
#pragma unroll
    for (int j = 0; j < 4; j++) {
        int jj = cb + 4 * l + j;
        float v = lrelu(fj[j] + bb[jj]);
        v = lrelu(v * ow[jj]);
        sf[wave][4 * l + j] = v;
    }

    float o = 0.f;
    if (l < 32) {
        float h = b1[l];
#pragma unroll 4
        for (int j = 0; j < 256; j++) h += sf[wave][j] * w1[j * 32 + l];
        h = lrelu(h);
        o = h * w2[l];
    }
    o += __shfl_xor(o, 16); o += __shfl_xor(o, 8); o += __shfl_xor(o, 4);
    o += __shfl_xor(o, 2);  o += __shfl_xor(o, 1);
    if (l == 0) outp[t] = o + b2[0];
}

// ---------------------------------------------------------------------------
extern "C" void kernel_launch(void* const* d_in, const int* in_sizes, int n_in,
                              void* d_out, int out_size, void* d_ws, size_t ws_size,
                              hipStream_t stream) {
    const float* x   = (const float*)d_in[0];
    const float* w0  = (const float*)d_in[1];
    const float* b0  = (const float*)d_in[2];
    const float* w1  = (const float*)d_in[3];
    const float* g1  = (const float*)d_in[4];
    const float* be1 = (const float*)d_in[5];
    const float* w2  = (const float*)d_in[6];
    const float* g2  = (const float*)d_in[7];
    const float* be2 = (const float*)d_in[8];
    const float* w3  = (const float*)d_in[9];
    const float* g3  = (const float*)d_in[10];
    const float* be3 = (const float*)d_in[11];
    const float* w4  = (const float*)d_in[12];
    const float* g4  = (const float*)d_in[13];
    const float* be4 = (const float*)d_in[14];
    const float* w5  = (const float*)d_in[15];
    const float* g5  = (const float*)d_in[16];
    const float* be5 = (const float*)d_in[17];
    const float* w6  = (const float*)d_in[18];
    const float* g6  = (const float*)d_in[19];
    const float* be6 = (const float*)d_in[20];
    const float* wg  = (const float*)d_in[21];
    const float* bw  = (const float*)d_in[22];
    const float* bbp = (const float*)d_in[23];
    const float* owp = (const float*)d_in[24];
    const float* cw1 = (const float*)d_in[25];
    const float* cb1 = (const float*)d_in[26];
    const float* cw2 = (const float*)d_in[27];
    const float* cb2 = (const float*)d_in[28];

    char* W = (char*)d_ws;
    float2* ssb = (float2*)W;
    float2* ss1 = ssb;
    float2* ss2 = ssb + 64;
    float2* ss3 = ssb + 192;
    float2* ss4 = ssb + 320;
    float2* ss5 = ssb + 576;
    float2* ss6 = ssb + 832;
    double2* part = (double2*)(W + 16384);   // 128 KiB, ends at 147456

    // Layout (max simultaneous span 103,989,248 B; proven-pass was 100.93 MB,
    // proven-fail 173.6 MB — betting ws >= ~104 MB; revert to quarters if 0.15 garbage)
    char* BIG = W + 147456;
    float* h0p = (float*)(BIG);               // (4,64,258,260) 68.69 MB  [0,68.7M)
    float* h1  = (float*)(BIG + 70287360);    // (8,64,128,128) 32 MiB    [70.3M,103.8M)
    float* h2p = (float*)(BIG);               // (8,128,130,132) 70.29 MB [0,70.3M)  (h0p dead)
    float* h3p = (float*)(BIG + 70287360);    // (8,128,66,68) 18.4 MB    (h1 dead)
    float* h4p = (float*)(BIG);               // (8,256,66,68) 36.77 MB   (h2p dead)
    float* h5p = (float*)(BIG + 36765696);    // (8,256,66,68)            (h3p dead)
    float* h6  = (float*)(BIG);               // (8,256,64,64) 32 MiB     (h4p dead)
    float* tok = (float*)(BIG + 36765696);    // (8,4096,256) 32 MiB      (h5p dead)

    // zero h0p borders once (conv0 halves only write interior)
    bnact_k<<<256, 256, 0, stream>>>(h0p, nullptr, 64, 256, 256, 258, 260);
    // conv0 (padded out) + conv1 (async) per batch-half
    for (int half = 0; half < 2; half++) {
        conv0_k<<<dim3(64, 4, 4), 256, 0, stream>>>(
            x + (size_t)half * 4 * 3 * 65536, w0, b0, h0p);
        c4x4p_k<8><<<dim3(16, 4, 8), 256, 0, stream>>>(
            h0p, w1, h1 + (size_t)half * 4 * 64 * 16384,
            64, 64, 256, 258, 260, 128, 128, 0);
    }
    stats_k<<<dim3(32, 64), 256, 0, stream>>>(h1, part, 64, 7, 7, 128, 128, 0);
    bnfin_k<<<1, 256, 0, stream>>>(part, 32, 64, 1.0 / 131072.0, g1, be1, ss1);
    // conv2 3x3 (masked+XFORM): h1 raw -> h2p raw padded interior
    c3x3_k<8, false><<<dim3(16, 8, 16), 256, 0, stream>>>(
        h1, w2, ss1, h2p, 64, 128, 128, 128, 128, 130, 132, 1);
    stats_k<<<dim3(32, 128), 256, 0, stream>>>(h2p, part, 128, 7, 7, 130, 132, 1);
    bnfin_k<<<1, 256, 0, stream>>>(part, 32, 128, 1.0 / 131072.0, g2, be2, ss2);
    bnact_k<<<1024, 256, 0, stream>>>(h2p, ss2, 128, 128, 128, 130, 132);
    // conv3 4x4 s2 async: h2p -> h3p raw padded interior
    c4x4p_k<8><<<dim3(4, 8, 16), 256, 0, stream>>>(
        h2p, w3, h3p, 128, 128, 128, 130, 132, 66, 68, 1);
    stats_k<<<dim3(32, 128), 256, 0, stream>>>(h3p, part, 128, 6, 6, 66, 68, 1);
    bnfin_k<<<1, 256, 0, stream>>>(part, 32, 128, 1.0 / 32768.0, g3, be3, ss3);
    bnact_k<<<1024, 256, 0, stream>>>(h3p, ss3, 128, 64, 64, 66, 68);
    // conv4 3x3 padded async: h3p -> h4p
    c3x3_k<8, true><<<dim3(4, 8, 32), 256, 0, stream>>>(
        h3p, w4, nullptr, h4p, 128, 256, 64, 66, 68, 66, 68, 1);
    stats_k<<<dim3(32, 256), 256, 0, stream>>>(h4p, part, 256, 6, 6, 66, 68, 1);
    bnfin_k<<<1, 256, 0, stream>>>(part, 32, 256, 1.0 / 32768.0, g4, be4, ss4);
    bnact_k<<<2048, 256, 0, stream>>>(h4p, ss4, 256, 64, 64, 66, 68);
    // conv5 3x3 padded async: h4p -> h5p
    c3x3_k<8, true><<<dim3(4, 8, 32), 256, 0, stream>>>(
        h4p, w5, nullptr, h5p, 256, 256, 64, 66, 68, 66, 68, 1);
    stats_k<<<dim3(32, 256), 256, 0, stream>>>(h5p, part, 256, 6, 6, 66, 68, 1);
    bnfin_k<<<1, 256, 0, stream>>>(part, 32, 256, 1.0 / 32768.0, g5, be5, ss5);
    bnact_k<<<2048, 256, 0, stream>>>(h5p, ss5, 256, 64, 64, 66, 68);
    // conv6 3x3 padded async: h5p -> h6 unpadded raw
    c3x3_k<8, true><<<dim3(4, 8, 32), 256, 0, stream>>>(
        h5p, w6, nullptr, h6, 256, 256, 64, 66, 68, 64, 64, 0);
    stats_k<<<dim3(32, 256), 256, 0, stream>>>(h6, part, 256, 6, 6, 64, 64, 0);
    bnfin_k<<<1, 256, 0, stream>>>(part, 32, 256, 1.0 / 32768.0, g6, be6, ss6);
    // transpose + BN6 + lrelu -> tok
    transp_k<<<dim3(128, 8, 8), 256, 0, stream>>>(h6, ss6, tok);
    // token stage -> out fp32 (8,4096,1)
    token_k<<<8192, 256, 0, stream>>>(tok, wg, bw, bbp, owp, cw1, cb1, cw2, cb2,
                                      (float*)d_out);
}

// Round 13
// 2583.325 us; speedup vs baseline: 1.6466x; 1.0835x over previous
//
#include <hip/hip_runtime.h>

__device__ __forceinline__ float lrelu(float x) { return x >= 0.f ? x : 0.2f * x; }

typedef const __attribute__((address_space(1))) void* gas_ptr;
typedef __attribute__((address_space(3))) void* las_ptr;

// ---------------------------------------------------------------------------
// conv0: fp32 x (4,3,256,256) (half batch), w (64,3,3,3), s1 p1, +bias+lrelu
// -> ACTIVATED fp32 PADDED h0p (4,64,258,260), interior at (1,1)
// ---------------------------------------------------------------------------
__global__ __launch_bounds__(256) void conv0_k(const float* __restrict__ x,
                                               const float* __restrict__ w,
                                               const float* __restrict__ bias,
                                               float* __restrict__ out) {
    __shared__ float sIn[3][34][34];
    __shared__ float sW[27][16];
    const int H = 256;
    int tid = threadIdx.x, tx = tid & 31, ty = tid >> 5;
    int tX = (blockIdx.x & 7) * 32, tY = (blockIdx.x >> 3) * 32;
    int b = blockIdx.y, cog = blockIdx.z * 16;
    float acc[4][16] = {};
    const float* inB = x + (size_t)b * 3 * H * H;
    for (int idx = tid; idx < 3 * 1156; idx += 256) {
        int ci = idx / 1156, r = idx % 1156, iy = r / 34, ix = r % 34;
        int gy = tY - 1 + iy, gx = tX - 1 + ix;
        float v = 0.f;
        if ((unsigned)gy < 256u && (unsigned)gx < 256u)
            v = inB[(ci * H + gy) * H + gx];
        sIn[ci][iy][ix] = v;
    }
    for (int idx = tid; idx < 27 * 16; idx += 256) {
        int co = idx & 15, rest = idx >> 4;
        sW[rest][co] = w[(cog + co) * 27 + rest];
    }
    __syncthreads();
#pragma unroll
    for (int ci = 0; ci < 3; ci++)
#pragma unroll
        for (int dy = 0; dy < 3; dy++)
#pragma unroll
            for (int dx = 0; dx < 3; dx++) {
                float a0 = sIn[ci][ty + dy][tx + dx];
                float a1 = sIn[ci][ty + 8 + dy][tx + dx];
                float a2 = sIn[ci][ty + 16 + dy][tx + dx];
                float a3 = sIn[ci][ty + 24 + dy][tx + dx];
                const float* wp = sW[ci * 9 + dy * 3 + dx];
#pragma unroll
                for (int co = 0; co < 16; co++) {
                    float wv = wp[co];
                    acc[0][co] += a0 * wv; acc[1][co] += a1 * wv;
                    acc[2][co] += a2 * wv; acc[3][co] += a3 * wv;
                }
            }
    float* outB = out + (size_t)(b * 64 + cog) * 67080;   // 258*260
#pragma unroll
    for (int co = 0; co < 16; co++) {
        float bv = bias[cog + co];
#pragma unroll
        for (int r = 0; r < 4; r++)
            outB[(size_t)co * 67080 + (size_t)(tY + ty + 8 * r + 1) * 260 +
                 tX + tx + 1] = lrelu(acc[r][co] + bv);
    }
}

// ---------------------------------------------------------------------------
// Fused BN-stats epilogue helper: per-block per-channel (sum, sumsq) via
// fp32 LDS tree (256 threads), stored as double2 partials. red needs
// 2*COG*256 floats of free LDS (reused staging buffers post-barrier).
// ---------------------------------------------------------------------------
template <int COG>
__device__ __forceinline__ void stats_epilogue(float (&acc)[4][COG], float* red,
                                               double2* part, int cog,
                                               int slotBase, int S, int tid) {
#pragma unroll
    for (int c = 0; c < COG; c++) {
        float s = 0.f, q = 0.f;
#pragma unroll
        for (int j = 0; j < 4; j++) { float v = acc[j][c]; s += v; q += v * v; }
        red[c * 256 + tid] = s;
        red[COG * 256 + c * 256 + tid] = q;
    }
    __syncthreads();
    for (int off = 128; off; off >>= 1) {
        if (tid < off) {
#pragma unroll
            for (int c = 0; c < COG; c++) {
                red[c * 256 + tid] += red[c * 256 + tid + off];
                red[COG * 256 + c * 256 + tid] +=
                    red[COG * 256 + c * 256 + tid + off];
            }
        }
        __syncthreads();
    }
    if (tid < COG) {
        int slot = slotBase + blockIdx.y * gridDim.x + blockIdx.x;
        part[(size_t)(cog + tid) * S + slot].x = (double)red[tid * 256];
        part[(size_t)(cog + tid) * S + slot].y =
            (double)red[COG * 256 + tid * 256];
    }
}

// ---------------------------------------------------------------------------
// Async padded 4x4 s2 conv (conv1, conv3). Input ACTIVATED padded (Hp,Wp),
// interior at (1,1), borders zero, Wp%4==0. Pure global_load_lds staging
// (R11-proven LDS-linear pattern). Fused BN-stats partials in epilogue.
// ---------------------------------------------------------------------------
template <int COG>
__global__ __launch_bounds__(256) void c4x4p_k(const float* __restrict__ in,
                                               const float* __restrict__ w,
                                               float* __restrict__ out,
                                               double2* __restrict__ part,
                                               int slotBase, int S,
                                               int Cin, int Cout, int Hin,
                                               int Hp, int Wp,
                                               int oHp, int oWp, int oOff) {
    __shared__ float sIn[2][4488];            // 66 rows x 68 cols
    __shared__ float sW[2][16 * COG];
    const int Hout = Hin >> 1;
    const int tid = threadIdx.x, tx = tid & 31, ty = tid >> 5;
    const int tpr = Hout >> 5;
    const int tX = (blockIdx.x % tpr) * 32, tY = (blockIdx.x / tpr) * 32;
    const int b = blockIdx.y, cog = blockIdx.z * COG;
    const int HWin = Hp * Wp;
    const float* inB = in + (size_t)b * Cin * HWin;
    const int wvbase = tid & ~63;

    int gOff[5]; int lOff[5]; bool act[5];
#pragma unroll
    for (int r = 0; r < 5; r++) {
        int idx = tid + r * 256;
        bool a = idx < 1122;                  // 66 rows x 17 float4
        int row = idx / 17, c4 = idx % 17;
        gOff[r] = a ? ((2 * tY + row) * Wp + 2 * tX + 4 * c4) : 0;
        lOff[r] = (r * 256 + wvbase) * 4;
        act[r] = a;
    }
    const int wco = tid % COG, wt = tid / COG;
    const int wgo = ((cog + wco) * Cin) * 16 + wt;
    const bool wact = tid < 16 * COG;

    float acc[4][COG];
#pragma unroll
    for (int j = 0; j < 4; j++)
#pragma unroll
        for (int c = 0; c < COG; c++) acc[j][c] = 0.f;

#pragma unroll
    for (int r = 0; r < 5; r++)
        if (act[r])
            __builtin_amdgcn_global_load_lds((gas_ptr)(inB + gOff[r]),
                                             (las_ptr)(&sIn[0][lOff[r]]), 16, 0, 0);
    if (wact)
        __builtin_amdgcn_global_load_lds((gas_ptr)(w + wgo),
                                         (las_ptr)(&sW[0][wvbase]), 4, 0, 0);
    __syncthreads();

    for (int k = 0; k < Cin; k++) {
        const int cur = k & 1, nb = cur ^ 1;
        const bool more = (k + 1) < Cin;
        if (more) {
            const float* p = inB + (size_t)(k + 1) * HWin;
#pragma unroll
            for (int r = 0; r < 5; r++)
                if (act[r])
                    __builtin_amdgcn_global_load_lds(
                        (gas_ptr)(p + gOff[r]),
                        (las_ptr)(&sIn[nb][lOff[r]]), 16, 0, 0);
            if (wact)
                __builtin_amdgcn_global_load_lds(
                    (gas_ptr)(w + wgo + (k + 1) * 16),
                    (las_ptr)(&sW[nb][wvbase]), 4, 0, 0);
        }
        const float* sI = sIn[cur];
        const float* sw = sW[cur];
#pragma unroll
        for (int dy = 0; dy < 4; dy++)
#pragma unroll
            for (int dx = 0; dx < 4; dx++) {
                const float* bp = sI + (2 * ty + dy) * 68 + 2 * tx + dx;
                float a0 = bp[0];
                float a1 = bp[16 * 68];
                float a2 = bp[32 * 68];
                float a3 = bp[48 * 68];
                const float* wp = sw + (dy * 4 + dx) * COG;
#pragma unroll
                for (int c = 0; c < COG; c++) {
                    float wv = wp[c];
                    acc[0][c] += a0 * wv; acc[1][c] += a1 * wv;
                    acc[2][c] += a2 * wv; acc[3][c] += a3 * wv;
                }
            }
        __syncthreads();
    }

    float* outB = out + (size_t)(b * Cout + cog) * oHp * oWp;
#pragma unroll
    for (int c = 0; c < COG; c++)
#pragma unroll
        for (int r = 0; r < 4; r++)
            outB[(size_t)c * oHp * oWp +
                 (size_t)(tY + ty + 8 * r + oOff) * oWp + tX + tx + oOff] =
                acc[r][c];
    stats_epilogue<COG>(acc, &sIn[0][0], part, cog, slotBase, S, tid);
}

// ---------------------------------------------------------------------------
// Async padded 3x3 s1 conv, 6-row register reuse, double-buffered LDS,
// global_load_lds staging. Fused BN-stats partials in epilogue.
// VGPR notes: R8 (cap 64 -> spill) and R10 (COG16 -> 2 waves/SIMD) both
// regressed; COG=8 async (~56 VGPR) is the sweet spot.
// ---------------------------------------------------------------------------
template <int COG>
__global__ __launch_bounds__(256) void c3x3_k(const float* __restrict__ in,
                                              const float* __restrict__ w,
                                              float* __restrict__ out,
                                              double2* __restrict__ part,
                                              int slotBase, int S,
                                              int Cin, int Cout, int H,
                                              int Hp, int Wp,
                                              int oHp, int oWp, int oOff) {
    constexpr int RS = 36;
    constexpr int CI = 34 * RS;               // 1224
    __shared__ float sIn[2][2 * CI];
    __shared__ float sW[2][18 * COG];
    const int tid = threadIdx.x, tx = tid & 31, ty = tid >> 5;
    const int tpr = H >> 5;
    const int tX = (blockIdx.x % tpr) * 32, tY = (blockIdx.x / tpr) * 32;
    const int b = blockIdx.y, cog = blockIdx.z * COG;
    const int HWin = Hp * Wp;
    const float* inB = in + (size_t)b * Cin * HWin;
    const int wvbase = tid & ~63;

    int gOff[3]; int lOff[3]; bool act[3];
#pragma unroll
    for (int r = 0; r < 3; r++) {
        int idx = tid + r * 256;
        bool a = idx < 612;                   // 2 cins x 34 rows x 9 float4
        int ci = idx / 306, rem = idx % 306;
        int row = rem / 9, c4 = rem % 9;
        gOff[r] = a ? (ci * HWin + (tY + row) * Wp + tX + 4 * c4) : 0;
        lOff[r] = (r * 256 + wvbase) * 4;
        act[r] = a;
    }
    constexpr int NW = (18 * COG + 255) / 256;
    int wgo[NW]; bool wact[NW];
#pragma unroll
    for (int r = 0; r < NW; r++) {
        int widx = tid + r * 256;
        bool a = widx < 18 * COG;
        int co = widx % COG, rest = widx / COG;
        int ci = rest / 9, t = rest % 9;
        wgo[r] = a ? (((cog + co) * Cin + ci) * 9 + t) : 0;
        wact[r] = a;
    }

    float acc[4][COG];
#pragma unroll
    for (int j = 0; j < 4; j++)
#pragma unroll
        for (int c = 0; c < COG; c++) acc[j][c] = 0.f;

    const int steps = Cin >> 1;

#pragma unroll
    for (int r = 0; r < 3; r++)
        if (act[r])
            __builtin_amdgcn_global_load_lds(
                (gas_ptr)(inB + gOff[r]),
                (las_ptr)(&sIn[0][lOff[r]]), 16, 0, 0);
#pragma unroll
    for (int r = 0; r < NW; r++)
        if (wact[r])
            __builtin_amdgcn_global_load_lds(
                (gas_ptr)(w + wgo[r]),
                (las_ptr)(&sW[0][r * 256 + wvbase]), 4, 0, 0);
    __syncthreads();

    for (int k = 0; k < steps; k++) {
        const int cur = k & 1;
        const int nb = cur ^ 1;
        const bool more = (k + 1) < steps;
        if (more) {
            const int c0n = 2 * (k + 1);
            const float* p = inB + (size_t)c0n * HWin;
            const float* wp2 = w + (size_t)c0n * 9;
#pragma unroll
            for (int r = 0; r < 3; r++)
                if (act[r])
                    __builtin_amdgcn_global_load_lds(
                        (gas_ptr)(p + gOff[r]),
                        (las_ptr)(&sIn[nb][lOff[r]]), 16, 0, 0);
#pragma unroll
            for (int r = 0; r < NW; r++)
                if (wact[r])
                    __builtin_amdgcn_global_load_lds(
                        (gas_ptr)(wp2 + wgo[r]),
                        (las_ptr)(&sW[nb][r * 256 + wvbase]), 4, 0, 0);
        }
        const float* sI = sIn[cur];
        const float* sw = sW[cur];
#pragma unroll
        for (int ci = 0; ci < 2; ci++)
#pragma unroll
            for (int dx = 0; dx < 3; dx++) {
                const float* bp = sI + ci * CI + (4 * ty) * RS + tx + dx;
                float a[6];
#pragma unroll
                for (int j = 0; j < 6; j++) a[j] = bp[j * RS];
#pragma unroll
                for (int dy = 0; dy < 3; dy++) {
                    const float* wp = sw + (ci * 9 + dy * 3 + dx) * COG;
#pragma unroll
                    for (int c = 0; c < COG; c++) {
                        float wv = wp[c];
                        acc[0][c] += a[0 + dy] * wv;
                        acc[1][c] += a[1 + dy] * wv;
                        acc[2][c] += a[2 + dy] * wv;
                        acc[3][c] += a[3 + dy] * wv;
                    }
                }
            }
        __syncthreads();
    }

    float* outB = out + (size_t)(b * Cout + cog) * oHp * oWp;
#pragma unroll
    for (int c = 0; c < COG; c++)
#pragma unroll
        for (int j = 0; j < 4; j++)
            outB[(size_t)c * oHp * oWp +
                 (size_t)(tY + 4 * ty + j + oOff) * oWp + tX + tx + oOff] =
                acc[j][c];
    stats_epilogue<COG>(acc, &sIn[0][0], part, cog, slotBase, S, tid);
}

// ---------------------------------------------------------------------------
// bnfin: fp64 combine of per-block partials -> per-channel (scale, shift).
// ---------------------------------------------------------------------------
__global__ void bnfin_k(const double2* __restrict__ part, int S, int C, double invN,
                        const float* __restrict__ g, const float* __restrict__ bb,
                        float2* __restrict__ ss) {
    int c = threadIdx.x;
    if (c >= C) return;
    double sum = 0.0, sq = 0.0;
    for (int s = 0; s < S; s++) {
        double2 p = part[(size_t)c * S + s];
        sum += p.x; sq += p.y;
    }
    double m = sum * invN;
    double v = sq * invN - m * m;
    double sc = (double)g[c] / sqrt(v + 1e-5);
    ss[c] = make_float2((float)sc, (float)((double)bb[c] - m * sc));
}

// ---------------------------------------------------------------------------
// bnact: zero padded border; if ss != nullptr also transform interior with
// lrelu(sc*x+sh) in place. One block per (b,c) plane, C power of two.
// ---------------------------------------------------------------------------
__global__ __launch_bounds__(256) void bnact_k(float* __restrict__ p,
                                               const float2* __restrict__ ss,
                                               int C, int H, int W,
                                               int Hp, int Wp) {
    int pc = blockIdx.x;
    int c = pc & (C - 1);
    float2 t = ss ? ss[c] : make_float2(1.f, 0.f);
    bool xf = (ss != nullptr);
    float* pl = p + (size_t)pc * Hp * Wp;
    int n = Hp * Wp;
    for (int i = threadIdx.x; i < n; i += 256) {
        int y = i / Wp, x = i - y * Wp;
        bool inter = (y >= 1) && (y <= H) && (x >= 1) && (x <= W);
        if (!inter) pl[i] = 0.f;
        else if (xf) { float v = pl[i]; pl[i] = lrelu(t.x * v + t.y); }
    }
}

// ---------------------------------------------------------------------------
// h6 raw (8,256,64,64) + BN6+lrelu -> tok (8,4096,256)
// ---------------------------------------------------------------------------
__global__ __launch_bounds__(256) void transp_k(const float* __restrict__ h6,
                                                const float2* __restrict__ ss,
                                                float* __restrict__ tok) {
    __shared__ float sT[32][33];
    int tx = threadIdx.x & 31, ty = threadIdx.x >> 5;
    int n0 = blockIdx.x * 32, d0 = blockIdx.y * 32, b = blockIdx.z;
    const float* hb = h6 + ((size_t)b * 256 + d0) * 4096 + n0;
#pragma unroll
    for (int r = 0; r < 4; r++) {
        int d = ty + 8 * r;
        float2 t = ss[d0 + d];
        sT[d][tx] = lrelu(t.x * hb[d * 4096 + tx] + t.y);
    }
    __syncthreads();
    float* tb = tok + ((size_t)b * 4096 + n0) * 256 + d0;
#pragma unroll
    for (int r = 0; r < 4; r++) {
        int n = ty + 8 * r;
        tb[n * 256 + tx] = sT[tx][n];
    }
}

// ---------------------------------------------------------------------------
// Token stage: gating argmax, selected-expert body slice, ortho, cls MLP.
// ---------------------------------------------------------------------------
__global__ __launch_bounds__(256) void token_k(const float* __restrict__ tok,
                                               const float* __restrict__ wg,
                                               const float* __restrict__ bw,
                                               const float* __restrict__ bb,
                                               const float* __restrict__ ow,
                                               const float* __restrict__ w1,
                                               const float* __restrict__ b1,
                                               const float* __restrict__ w2,
                                               const float* __restrict__ b2,
                                               float* __restrict__ outp) {
    __shared__ float sf[4][256];
    const int tid = threadIdx.x, wave = tid >> 6, l = tid & 63;
    const int t = blockIdx.x * 4 + wave;
    const float4 tv = reinterpret_cast<const float4*>(tok + (size_t)t * 256)[l];
    sf[wave][4 * l + 0] = tv.x; sf[wave][4 * l + 1] = tv.y;
    sf[wave][4 * l + 2] = tv.z; sf[wave][4 * l + 3] = tv.w;

    float lg[12];
#pragma unroll
    for (int e = 0; e < 12; e++) lg[e] = 0.f;
    const float tj[4] = {tv.x, tv.y, tv.z, tv.w};
#pragma unroll
    for (int j = 0; j < 4; j++) {
        const float* wr = wg + (4 * l + j) * 12;
#pragma unroll
        for (int e = 0; e < 12; e++) lg[e] += tj[j] * wr[e];
    }
#pragma unroll
    for (int off = 32; off > 0; off >>= 1) {
#pragma unroll
        for (int e = 0; e < 12; e++) lg[e] += __shfl_xor(lg[e], off);
    }
    int idx = 0; float best = lg[0];
#pragma unroll
    for (int e = 1; e < 12; e++)
        if (lg[e] > best) { best = lg[e]; idx = e; }
    const int cb = idx * 256;

    float f0 = 0.f, f1 = 0.f, f2 = 0.f, f3 = 0.f;
    const float* bwp = bw + cb + 4 * l;
#pragma unroll 4
    for (int d = 0; d < 256; d++) {
        const float td = sf[wave][d];
        const float4 wv = *reinterpret_cast<const float4*>(bwp + (size_t)d * 3072);
        f0 += td * wv.x; f1 += td * wv.y;
        f2 += td * wv.z; f3 += td * wv.w;
    }
    float fj[4] = {f0, f1, f2, f3};
#pragma unroll
    for (int j = 0; j < 4; j++) {
        int jj = cb + 4 * l + j;
        float v = lrelu(fj[j] + bb[jj]);
        v = lrelu(v * ow[jj]);
        sf[wave][4 * l + j] = v;
    }

    float o = 0.f;
    if (l < 32) {
        float h = b1[l];
#pragma unroll 4
        for (int j = 0; j < 256; j++) h += sf[wave][j] * w1[j * 32 + l];
        h = lrelu(h);
        o = h * w2[l];
    }
    o += __shfl_xor(o, 16); o += __shfl_xor(o, 8); o += __shfl_xor(o, 4);
    o += __shfl_xor(o, 2);  o += __shfl_xor(o, 1);
    if (l == 0) outp[t] = o + b2[0];
}

// ---------------------------------------------------------------------------
extern "C" void kernel_launch(void* const* d_in, const int* in_sizes, int n_in,
                              void* d_out, int out_size, void* d_ws, size_t ws_size,
                              hipStream_t stream) {
    const float* x   = (const float*)d_in[0];
    const float* w0  = (const float*)d_in[1];
    const float* b0  = (const float*)d_in[2];
    const float* w1  = (const float*)d_in[3];
    const float* g1  = (const float*)d_in[4];
    const float* be1 = (const float*)d_in[5];
    const float* w2  = (const float*)d_in[6];
    const float* g2  = (const float*)d_in[7];
    const float* be2 = (const float*)d_in[8];
    const float* w3  = (const float*)d_in[9];
    const float* g3  = (const float*)d_in[10];
    const float* be3 = (const float*)d_in[11];
    const float* w4  = (const float*)d_in[12];
    const float* g4  = (const float*)d_in[13];
    const float* be4 = (const float*)d_in[14];
    const float* w5  = (const float*)d_in[15];
    const float* g5  = (const float*)d_in[16];
    const float* be5 = (const float*)d_in[17];
    const float* w6  = (const float*)d_in[18];
    const float* g6  = (const float*)d_in[19];
    const float* be6 = (const float*)d_in[20];
    const float* wg  = (const float*)d_in[21];
    const float* bw  = (const float*)d_in[22];
    const float* bbp = (const float*)d_in[23];
    const float* owp = (const float*)d_in[24];
    const float* cw1 = (const float*)d_in[25];
    const float* cb1 = (const float*)d_in[26];
    const float* cw2 = (const float*)d_in[27];
    const float* cb2 = (const float*)d_in[28];

    char* W = (char*)d_ws;
    float2* ssb = (float2*)W;                 // ss tables in [0,16K)
    float2* ss1 = ssb;
    float2* ss2 = ssb + 64;
    float2* ss3 = ssb + 192;
    float2* ss4 = ssb + 320;
    float2* ss5 = ssb + 576;
    float2* ss6 = ssb + 832;
    double2* part = (double2*)(W + 16384);    // up to 256 KiB (conv2: 128ch x 128 slots)

    // Big region @278528. Max span = 278528 + 105,431,040 = 105.71 MB
    // (R12 proved 104.0 MB OK, R6 proved 173.6 MB fails; bet ws >= ~112 MB).
    char* BIG = W + 278528;
    float* h0p = (float*)(BIG);               // (4,64,258,260) 68.69 MB [0,68.7M)
    float* h1p = (float*)(BIG + 70287360);    // (8,64,130,132) 35.14 MB [70.3M,105.4M)
    float* h2p = (float*)(BIG);               // (8,128,130,132) 70.29 MB [0,70.3M)
    float* h3p = (float*)(BIG + 70287360);    // (8,128,66,68) 18.4 MB (h1p dead)
    float* h4p = (float*)(BIG);               // (8,256,66,68) 36.77 MB (h2p dead)
    float* h5p = (float*)(BIG + 36765696);    // (8,256,66,68) (h3p dead after conv4)
    float* h6  = (float*)(BIG);               // (8,256,64,64) 32 MiB (h4p dead)
    float* tok = (float*)(BIG + 36765696);    // (8,4096,256) 32 MiB (h5p dead)

    // zero h0p borders once (conv0 halves only write interior)
    bnact_k<<<256, 256, 0, stream>>>(h0p, nullptr, 64, 256, 256, 258, 260);
    // conv0 (padded out) + conv1 (async, padded out, fused stats) per half
    for (int half = 0; half < 2; half++) {
        conv0_k<<<dim3(64, 4, 4), 256, 0, stream>>>(
            x + (size_t)half * 4 * 3 * 65536, w0, b0, h0p);
        c4x4p_k<8><<<dim3(16, 4, 8), 256, 0, stream>>>(
            h0p, w1, h1p + (size_t)half * 4 * 64 * 17160, part, half * 64, 128,
            64, 64, 256, 258, 260, 130, 132, 1);
    }
    bnfin_k<<<1, 256, 0, stream>>>(part, 128, 64, 1.0 / 131072.0, g1, be1, ss1);
    bnact_k<<<512, 256, 0, stream>>>(h1p, ss1, 64, 128, 128, 130, 132);
    // conv2 3x3 async: h1p -> h2p padded interior, fused stats (S=128)
    c3x3_k<8><<<dim3(16, 8, 16), 256, 0, stream>>>(
        h1p, w2, h2p, part, 0, 128, 64, 128, 128, 130, 132, 130, 132, 1);
    bnfin_k<<<1, 256, 0, stream>>>(part, 128, 128, 1.0 / 131072.0, g2, be2, ss2);
    bnact_k<<<1024, 256, 0, stream>>>(h2p, ss2, 128, 128, 128, 130, 132);
    // conv3 4x4 s2 async: h2p -> h3p padded interior, fused stats (S=32)
    c4x4p_k<8><<<dim3(4, 8, 16), 256, 0, stream>>>(
        h2p, w3, h3p, part, 0, 32, 128, 128, 128, 130, 132, 66, 68, 1);
    bnfin_k<<<1, 256, 0, stream>>>(part, 32, 128, 1.0 / 32768.0, g3, be3, ss3);
    bnact_k<<<1024, 256, 0, stream>>>(h3p, ss3, 128, 64, 64, 66, 68);
    // conv4 3x3 async: h3p -> h4p, fused stats
    c3x3_k<8><<<dim3(4, 8, 32), 256, 0, stream>>>(
        h3p, w4, h4p, part, 0, 32, 128, 256, 64, 66, 68, 66, 68, 1);
    bnfin_k<<<1, 256, 0, stream>>>(part, 32, 256, 1.0 / 32768.0, g4, be4, ss4);
    bnact_k<<<2048, 256, 0, stream>>>(h4p, ss4, 256, 64, 64, 66, 68);
    // conv5 3x3 async: h4p -> h5p, fused stats
    c3x3_k<8><<<dim3(4, 8, 32), 256, 0, stream>>>(
        h4p, w5, h5p, part, 0, 32, 256, 256, 64, 66, 68, 66, 68, 1);
    bnfin_k<<<1, 256, 0, stream>>>(part, 32, 256, 1.0 / 32768.0, g5, be5, ss5);
    bnact_k<<<2048, 256, 0, stream>>>(h5p, ss5, 256, 64, 64, 66, 68);
    // conv6 3x3 async: h5p -> h6 unpadded, fused stats
    c3x3_k<8><<<dim3(4, 8, 32), 256, 0, stream>>>(
        h5p, w6, h6, part, 0, 32, 256, 256, 64, 66, 68, 64, 64, 0);
    bnfin_k<<<1, 256, 0, stream>>>(part, 32, 256, 1.0 / 32768.0, g6, be6, ss6);
    // transpose + BN6 + lrelu -> tok
    transp_k<<<dim3(128, 8, 8), 256, 0, stream>>>(h6, ss6, tok);
    // token stage -> out fp32 (8,4096,1)
    token_k<<<8192, 256, 0, stream>>>(tok, wg, bw, bbp, owp, cw1, cb1, cw2, cb2,
                                      (float*)d_out);
}